// Round 1
// baseline (4242.094 us; speedup 1.0000x reference)
//
#include <hip/hip_runtime.h>
#include <math.h>

#define HID   1024
#define NHEAD 16
#define DHEAD 64
#define BATCH 2
#define SEQ   2048

#define TQ 32
#define TK 32
#define NW 63   // TQ+TK-1 distinct rel-shift rows per tile pair

__device__ __forceinline__ float dot4(float4 a, float4 b, float acc) {
    acc = fmaf(a.x, b.x, acc); acc = fmaf(a.y, b.y, acc);
    acc = fmaf(a.z, b.z, acc); acc = fmaf(a.w, b.w, acc);
    return acc;
}

// ---------------- GEMM: C[M,1024] = A[M,1024] @ W[1024,1024] (+ bias) -------
// 64x64 tile, BK=16, 256 threads, 4x4 microtile per thread, fp32.
__global__ __launch_bounds__(256) void gemm_bias_kernel(
    const float* __restrict__ A, const float* __restrict__ W,
    const float* __restrict__ bias, float* __restrict__ C)
{
    __shared__ float As[64][17];   // [m][k], +1 pad: conflict-free tr-broadcast reads
    __shared__ float Ws[16][64];   // [k][n]
    const int tid = threadIdx.x;
    const int bm = blockIdx.y * 64;
    const int bn = blockIdx.x * 64;
    const int tr = tid >> 4;       // 0..15
    const int tc = tid & 15;       // 0..15

    float acc[4][4];
#pragma unroll
    for (int i = 0; i < 4; i++)
#pragma unroll
        for (int j = 0; j < 4; j++) acc[i][j] = 0.f;

    const int arow = tid >> 2;          // 0..63
    const int akq  = (tid & 3) * 4;     // 0,4,8,12
    const int wkk  = tid >> 6;          // 0..3
    const int wcc  = tid & 63;

    for (int k0 = 0; k0 < HID; k0 += 16) {
        float4 av = *(const float4*)(A + (size_t)(bm + arow) * HID + k0 + akq);
        As[arow][akq + 0] = av.x; As[arow][akq + 1] = av.y;
        As[arow][akq + 2] = av.z; As[arow][akq + 3] = av.w;
#pragma unroll
        for (int e = 0; e < 4; e++)
            Ws[wkk + e * 4][wcc] = W[(size_t)(k0 + wkk + e * 4) * HID + bn + wcc];
        __syncthreads();
#pragma unroll
        for (int kk = 0; kk < 16; kk++) {
            float a[4];
            a[0] = As[tr * 4 + 0][kk]; a[1] = As[tr * 4 + 1][kk];
            a[2] = As[tr * 4 + 2][kk]; a[3] = As[tr * 4 + 3][kk];
            float4 b4 = *(const float4*)&Ws[kk][tc * 4];
            float bb[4] = {b4.x, b4.y, b4.z, b4.w};
#pragma unroll
            for (int i = 0; i < 4; i++)
#pragma unroll
                for (int j = 0; j < 4; j++)
                    acc[i][j] = fmaf(a[i], bb[j], acc[i][j]);
        }
        __syncthreads();
    }
#pragma unroll
    for (int i = 0; i < 4; i++) {
        const int row = bm + tr * 4 + i;
        const int col = bn + tc * 4;
        float4 o;
        o.x = acc[i][0]; o.y = acc[i][1]; o.z = acc[i][2]; o.w = acc[i][3];
        if (bias) {
            const float4 bv = *(const float4*)(bias + col);
            o.x += bv.x; o.y += bv.y; o.z += bv.z; o.w += bv.w;
        }
        *(float4*)(C + (size_t)row * HID + col) = o;
    }
}

// ---------------- Flash-style rel-attention ---------------------------------
// Grid: (SEQ/TQ, NHEAD, BATCH), 256 threads.
// Shifted BD[i,j]: rr = SEQ-1+j-i.
//   rr <  SEQ : (q_i   + rrb) . rk[rr]
//   rr == SEQ : 0
//   rr >  SEQ : (q_{i+1}+rrb) . rk[rr-SEQ-1]
// With l = jl + (TQ-1) - il, rr = base1 + l, base1 = SEQ + j0 - i0 - TQ;
// the rk row and case depend only on l -> one LDS window rkc[l].
__global__ __launch_bounds__(256) void rel_attn_kernel(
    const float* __restrict__ Q, const float* __restrict__ K,
    const float* __restrict__ V, const float* __restrict__ Rk,
    const float* __restrict__ rwb, const float* __restrict__ rrb,
    float* __restrict__ Out)
{
    __shared__ float qs[TQ + 1][DHEAD];      // q rows i0..i0+TQ (raw, no bias)
    __shared__ float kt[TK][DHEAD + 4];      // +4 pad: row-varying reads
    __shared__ float vt[TK][DHEAD];          // row fixed per access -> no pad
    __shared__ float rkc[NW][DHEAD + 4];     // rel-shift rk window
    __shared__ float ptile[TQ][36];          // probs tile, stride 36 (16B-aligned rows)
    __shared__ float acb[TK];                // rwb . k_j
    __shared__ float bdb[NW];                // rrb . rkc_l
    __shared__ float rwb_s[DHEAD], rrb_s[DHEAD];
    __shared__ float row_m[TQ], row_l[TQ], row_alpha[TQ];

    const int tid = threadIdx.x;
    const int i0 = blockIdx.x * TQ;
    const int n  = blockIdx.y;
    const int b  = blockIdx.z;

    const float* Qb  = Q  + (size_t)b * SEQ * HID + n * DHEAD;
    const float* Kb  = K  + (size_t)b * SEQ * HID + n * DHEAD;
    const float* Vb  = V  + (size_t)b * SEQ * HID + n * DHEAD;
    const float* Rkb = Rk + n * DHEAD;

    // preload q rows (TQ+1 of them), head bias vectors, init row state
    for (int idx = tid; idx < (TQ + 1) * 16; idx += 256) {
        int rq = idx >> 4, c4 = (idx & 15) * 4;
        int gi = i0 + rq;
        float4 qv = make_float4(0.f, 0.f, 0.f, 0.f);
        if (gi < SEQ) qv = *(const float4*)(Qb + (size_t)gi * HID + c4);
        *(float4*)&qs[rq][c4] = qv;
    }
    if (tid < 16) {
        *(float4*)&rwb_s[tid * 4] = *(const float4*)(rwb + n * DHEAD + tid * 4);
    } else if (tid < 32) {
        int t = tid - 16;
        *(float4*)&rrb_s[t * 4] = *(const float4*)(rrb + n * DHEAD + t * 4);
    }
    if (tid < TQ) { row_m[tid] = -3.0e38f; row_l[tid] = 0.f; }

    float o[8];
#pragma unroll
    for (int e = 0; e < 8; e++) o[e] = 0.f;

    const int mi = tid >> 4, mj = tid & 15;  // score phase: 2x2 per thread
    const int il0 = mi * 2, jl0 = mj * 2;
    const int prow = tid >> 3, dc = (tid & 7) * 8;  // PV phase: row, 8 d-elems

    for (int j0 = 0; j0 < SEQ; j0 += TK) {
        __syncthreads();   // protect prev iteration's LDS consumers
        // stage K/V tiles
        for (int idx = tid; idx < TK * 16; idx += 256) {
            int r = idx >> 4, c4 = (idx & 15) * 4;
            *(float4*)&kt[r][c4] = *(const float4*)(Kb + (size_t)(j0 + r) * HID + c4);
            *(float4*)&vt[r][c4] = *(const float4*)(Vb + (size_t)(j0 + r) * HID + c4);
        }
        const int base1 = SEQ + j0 - i0 - TQ;
        for (int idx = tid; idx < NW * 16; idx += 256) {
            int l = idx >> 4, c4 = (idx & 15) * 4;
            int rr = base1 + l;
            float4 rv = make_float4(0.f, 0.f, 0.f, 0.f);
            if (rr < SEQ)      rv = *(const float4*)(Rkb + (size_t)rr * HID + c4);
            else if (rr > SEQ) rv = *(const float4*)(Rkb + (size_t)(rr - SEQ - 1) * HID + c4);
            *(float4*)&rkc[l][c4] = rv;
        }
        __syncthreads();
        // per-tile bias dot products (factored out of AC/BD)
        if (tid < TK) {
            float a = 0.f;
#pragma unroll
            for (int d = 0; d < DHEAD; d++) a = fmaf(rwb_s[d], kt[tid][d], a);
            acb[tid] = a;
        } else if (tid < TK + NW) {
            int l = tid - TK;
            float a = 0.f;
#pragma unroll
            for (int d = 0; d < DHEAD; d++) a = fmaf(rrb_s[d], rkc[l][d], a);
            bdb[l] = a;
        }
        __syncthreads();

        // ---- scores: 2x2 microtile ----
        float s[2][2];
        {
            float s00 = 0.f, s01 = 0.f, s10 = 0.f, s11 = 0.f;
#pragma unroll
            for (int d4 = 0; d4 < 16; d4++) {
                float4 q0 = *(const float4*)&qs[il0    ][d4 * 4];
                float4 q1 = *(const float4*)&qs[il0 + 1][d4 * 4];
                float4 k0 = *(const float4*)&kt[jl0    ][d4 * 4];
                float4 k1 = *(const float4*)&kt[jl0 + 1][d4 * 4];
                s00 = dot4(q0, k0, s00); s01 = dot4(q0, k1, s01);
                s10 = dot4(q1, k0, s10); s11 = dot4(q1, k1, s11);
            }
            s[0][0] = s00 + acb[jl0];     s[0][1] = s01 + acb[jl0 + 1];
            s[1][0] = s10 + acb[jl0];     s[1][1] = s11 + acb[jl0 + 1];
        }
#pragma unroll
        for (int ei = 0; ei < 2; ei++)
#pragma unroll
            for (int ej = 0; ej < 2; ej++) {
                const int il = il0 + ei, jl = jl0 + ej;
                const int l = jl + (TQ - 1) - il;
                const int rr = base1 + l;
                float bd = 0.f;
                if (rr != SEQ) {
                    const float* qrow = qs[(rr < SEQ) ? il : (il + 1)];
                    const float* rrow = rkc[l];
#pragma unroll
                    for (int d4 = 0; d4 < 16; d4++) {
                        float4 qv = *(const float4*)&qrow[d4 * 4];
                        float4 rv = *(const float4*)&rrow[d4 * 4];
                        bd = dot4(qv, rv, bd);
                    }
                    bd += bdb[l];
                }
                s[ei][ej] = (s[ei][ej] + bd) * 0.125f;  // 1/sqrt(64)
            }

        // ---- online softmax (16 lanes own each row) ----
        float tm0 = fmaxf(s[0][0], s[0][1]);
        float tm1 = fmaxf(s[1][0], s[1][1]);
#pragma unroll
        for (int off = 1; off < 16; off <<= 1) {
            tm0 = fmaxf(tm0, __shfl_xor(tm0, off));
            tm1 = fmaxf(tm1, __shfl_xor(tm1, off));
        }
        const float mold0 = row_m[il0], mold1 = row_m[il0 + 1];
        const float mnew0 = fmaxf(mold0, tm0), mnew1 = fmaxf(mold1, tm1);
        float p00 = __expf(s[0][0] - mnew0), p01 = __expf(s[0][1] - mnew0);
        float p10 = __expf(s[1][0] - mnew1), p11 = __expf(s[1][1] - mnew1);
        ptile[il0    ][jl0] = p00; ptile[il0    ][jl0 + 1] = p01;
        ptile[il0 + 1][jl0] = p10; ptile[il0 + 1][jl0 + 1] = p11;
        float ps0 = p00 + p01, ps1 = p10 + p11;
#pragma unroll
        for (int off = 1; off < 16; off <<= 1) {
            ps0 += __shfl_xor(ps0, off);
            ps1 += __shfl_xor(ps1, off);
        }
        if (mj == 0) {
            const float a0 = __expf(mold0 - mnew0);
            const float a1 = __expf(mold1 - mnew1);
            row_alpha[il0] = a0;      row_alpha[il0 + 1] = a1;
            row_m[il0] = mnew0;       row_m[il0 + 1] = mnew1;
            row_l[il0] = row_l[il0] * a0 + ps0;
            row_l[il0 + 1] = row_l[il0 + 1] * a1 + ps1;
        }
        __syncthreads();

        // ---- PV accumulate (8 lanes x 8 d-elems own each row) ----
        const float alpha = row_alpha[prow];
#pragma unroll
        for (int e = 0; e < 8; e++) o[e] *= alpha;
#pragma unroll
        for (int j4 = 0; j4 < TK; j4 += 4) {
            float4 p4 = *(const float4*)&ptile[prow][j4];
            const float* v0 = &vt[j4    ][dc];
            const float* v1 = &vt[j4 + 1][dc];
            const float* v2 = &vt[j4 + 2][dc];
            const float* v3 = &vt[j4 + 3][dc];
#pragma unroll
            for (int e = 0; e < 8; e++) {
                float t = fmaf(p4.x, v0[e], o[e]);
                t = fmaf(p4.y, v1[e], t);
                t = fmaf(p4.z, v2[e], t);
                o[e] = fmaf(p4.w, v3[e], t);
            }
        }
    }

    // epilogue: normalize and store
    const float inv = 1.f / row_l[prow];
    const int gi = i0 + prow;
    float* op = Out + ((size_t)b * SEQ + gi) * HID + n * DHEAD + dc;
    float4 o0 = make_float4(o[0] * inv, o[1] * inv, o[2] * inv, o[3] * inv);
    float4 o1 = make_float4(o[4] * inv, o[5] * inv, o[6] * inv, o[7] * inv);
    *(float4*)(op + 0) = o0;
    *(float4*)(op + 4) = o1;
}

extern "C" void kernel_launch(void* const* d_in, const int* in_sizes, int n_in,
                              void* d_out, int out_size, void* d_ws, size_t ws_size,
                              hipStream_t stream) {
    const float* hs  = (const float*)d_in[0];
    const float* r   = (const float*)d_in[1];
    const float* rwb = (const float*)d_in[2];
    const float* rrb = (const float*)d_in[3];
    const float* Wq  = (const float*)d_in[4];
    const float* bq  = (const float*)d_in[5];
    const float* Wk  = (const float*)d_in[6];
    const float* bk  = (const float*)d_in[7];
    const float* Wv  = (const float*)d_in[8];
    const float* bv  = (const float*)d_in[9];
    const float* Wr  = (const float*)d_in[10];
    float* out = (float*)d_out;
    float* ws  = (float*)d_ws;

    // workspace layout (floats): Q | K | V | Rk  = 4M+4M+4M+2M = 58.7 MB
    float* Qp = ws;
    float* Kp = ws + (size_t)BATCH * SEQ * HID;
    float* Vp = ws + (size_t)2 * BATCH * SEQ * HID;
    float* Rp = ws + (size_t)3 * BATCH * SEQ * HID;

    dim3 blk(256);
    dim3 g_qkv(HID / 64, (BATCH * SEQ) / 64);
    gemm_bias_kernel<<<g_qkv, blk, 0, stream>>>(hs, Wq, bq, Qp);
    gemm_bias_kernel<<<g_qkv, blk, 0, stream>>>(hs, Wk, bk, Kp);
    gemm_bias_kernel<<<g_qkv, blk, 0, stream>>>(hs, Wv, bv, Vp);
    dim3 g_r(HID / 64, SEQ / 64);
    gemm_bias_kernel<<<g_r, blk, 0, stream>>>(r, Wr, nullptr, Rp);

    dim3 g_attn(SEQ / TQ, NHEAD, BATCH);
    rel_attn_kernel<<<g_attn, blk, 0, stream>>>(Qp, Kp, Vp, Rp, rwb, rrb, out);
}

// Round 2
// 966.594 us; speedup vs baseline: 4.3887x; 4.3887x over previous
//
#include <hip/hip_runtime.h>
#include <math.h>

#define HID   1024
#define NHEAD 16
#define DHEAD 64
#define BATCH 2
#define SEQ   2048

#define TQ 64
#define TK 64
#define NW 127      // TQ+TK-1 rel-shift band width
#define LDQ 72      // padded LDS stride (bf16 elems) for q/k/v/rkc/P
#define LDB 140     // padded LDS stride for BD band (bank-rotation 6 words/row)

typedef __bf16 bf16_t;
typedef bf16_t bf16x8 __attribute__((ext_vector_type(8)));
typedef bf16_t bf16x4 __attribute__((ext_vector_type(4)));
typedef float  f32x4  __attribute__((ext_vector_type(4)));

// ---------------- GEMM: C[M,1024] = A[M,1024] @ W[1024,1024] (+ bias) -------
// fp32 compute, bf16 head-split epilogue.
// vmode 0: C[((b*16+n)*2048+s)*64+d]   (Q, K, Rk)
// vmode 1: C[((b*16+n)*64+d)*2048+s]   (V transposed)
__global__ __launch_bounds__(256) void gemm_bias_bf16(
    const float* __restrict__ A, const float* __restrict__ W,
    const float* __restrict__ bias, bf16_t* __restrict__ C, int vmode)
{
    __shared__ float As[64][17];
    __shared__ float Ws[16][64];
    const int tid = threadIdx.x;
    const int bm = blockIdx.y * 64;
    const int bn = blockIdx.x * 64;
    const int tr = tid >> 4;
    const int tc = tid & 15;

    float acc[4][4];
#pragma unroll
    for (int i = 0; i < 4; i++)
#pragma unroll
        for (int j = 0; j < 4; j++) acc[i][j] = 0.f;

    const int arow = tid >> 2;
    const int akq  = (tid & 3) * 4;
    const int wkk  = tid >> 6;
    const int wcc  = tid & 63;

    for (int k0 = 0; k0 < HID; k0 += 16) {
        float4 av = *(const float4*)(A + (size_t)(bm + arow) * HID + k0 + akq);
        As[arow][akq + 0] = av.x; As[arow][akq + 1] = av.y;
        As[arow][akq + 2] = av.z; As[arow][akq + 3] = av.w;
#pragma unroll
        for (int e = 0; e < 4; e++)
            Ws[wkk + e * 4][wcc] = W[(size_t)(k0 + wkk + e * 4) * HID + bn + wcc];
        __syncthreads();
#pragma unroll
        for (int kk = 0; kk < 16; kk++) {
            float a[4];
            a[0] = As[tr * 4 + 0][kk]; a[1] = As[tr * 4 + 1][kk];
            a[2] = As[tr * 4 + 2][kk]; a[3] = As[tr * 4 + 3][kk];
            float4 b4 = *(const float4*)&Ws[kk][tc * 4];
            float bb[4] = {b4.x, b4.y, b4.z, b4.w};
#pragma unroll
            for (int i = 0; i < 4; i++)
#pragma unroll
                for (int j = 0; j < 4; j++)
                    acc[i][j] = fmaf(a[i], bb[j], acc[i][j]);
        }
        __syncthreads();
    }
    // bias
    if (bias) {
        const float4 bv = *(const float4*)(bias + bn + tc * 4);
#pragma unroll
        for (int i = 0; i < 4; i++) {
            acc[i][0] += bv.x; acc[i][1] += bv.y; acc[i][2] += bv.z; acc[i][3] += bv.w;
        }
    }
    if (vmode == 0) {
#pragma unroll
        for (int i = 0; i < 4; i++) {
            const int row = bm + tr * 4 + i;
            const int col = bn + tc * 4;
            const int bb = row >> 11, s = row & (SEQ - 1);
            const int nh = col >> 6, d = col & 63;
            bf16x4 pv;
#pragma unroll
            for (int j = 0; j < 4; j++) pv[j] = (bf16_t)acc[i][j];
            *(bf16x4*)(C + (((size_t)(bb * NHEAD + nh) * SEQ + s) * DHEAD + d)) = pv;
        }
    } else {
#pragma unroll
        for (int j = 0; j < 4; j++) {
            const int col = bn + tc * 4 + j;
            const int nh = col >> 6, d = col & 63;
            const int row0 = bm + tr * 4;
            const int bb = row0 >> 11, s0 = row0 & (SEQ - 1);
            bf16x4 pv;
#pragma unroll
            for (int i = 0; i < 4; i++) pv[i] = (bf16_t)acc[i][j];
            *(bf16x4*)(C + (((size_t)(bb * NHEAD + nh) * DHEAD + d) * SEQ + s0)) = pv;
        }
    }
}

// ---------------- MFMA flash rel-attention ----------------------------------
// Grid (SEQ/64, NH, B), 256 thr = 4 waves; wave w owns q rows [16w,16w+16).
// Per K-tile: AC = q.K^T (MFMA) + acb[j];  BD band q.rkc^T (MFMA) + bdb[l],
// stored to LDS, diagonal-gathered into scores; online softmax in C-layout;
// P->LDS->A-frag; PV MFMA. rr==SEQ zero is automatic (rkc row zeroed).
__global__ __launch_bounds__(256, 3) void rel_attn_mfma(
    const bf16_t* __restrict__ Qh, const bf16_t* __restrict__ Kh,
    const bf16_t* __restrict__ Vth, const bf16_t* __restrict__ Rkh,
    const float* __restrict__ rwb, const float* __restrict__ rrb,
    float* __restrict__ Out)
{
    __shared__ bf16_t qs[65 * LDQ];
    __shared__ bf16_t kt[64 * LDQ];
    __shared__ bf16_t vt[64 * LDQ];          // [d][key]
    __shared__ bf16_t uni[128 * LDQ];        // union: rkc(128*72) | BDband(65*140) | P(4*16*72)
    __shared__ float acb[64];
    __shared__ float bdb[128];
    __shared__ float rwb_s[64], rrb_s[64];

    const int tid = threadIdx.x;
    const int w = tid >> 6, lane = tid & 63;
    const int quad = lane >> 4, l16 = lane & 15;
    const int i0 = blockIdx.x * TQ;
    const int n = blockIdx.y, b = blockIdx.z;

    const bf16_t* Qb = Qh + ((size_t)(b * NHEAD + n) * SEQ + i0) * DHEAD;
    const bf16_t* Kb = Kh + (size_t)(b * NHEAD + n) * SEQ * DHEAD;
    const bf16_t* Vb = Vth + (size_t)(b * NHEAD + n) * DHEAD * SEQ;
    const bf16_t* Rb = Rkh + (size_t)n * SEQ * DHEAD;

    // block-start: q rows i0..i0+64 (zero OOB row), bias vectors
    for (int idx = tid; idx < 65 * 8; idx += 256) {
        int row = idx >> 3, c8 = (idx & 7) * 8;
        uint4 val = make_uint4(0, 0, 0, 0);
        if (i0 + row < SEQ) val = *(const uint4*)(Qb + row * DHEAD + c8);
        *(uint4*)&qs[row * LDQ + c8] = val;
    }
    if (tid < 64) rwb_s[tid] = rwb[n * DHEAD + tid];
    else if (tid < 128) rrb_s[tid - 64] = rrb[n * DHEAD + tid - 64];

    f32x4 o[4];
    float mprev[4], lsum[4];
#pragma unroll
    for (int t = 0; t < 4; t++) {
        o[t][0] = 0.f; o[t][1] = 0.f; o[t][2] = 0.f; o[t][3] = 0.f;
        mprev[t] = -3.0e38f; lsum[t] = 0.f;
    }

    for (int j0 = 0; j0 < SEQ; j0 += TK) {
        __syncthreads();                          // prev PV done -> restage
        for (int idx = tid; idx < 64 * 8; idx += 256) {
            int row = idx >> 3, c8 = (idx & 7) * 8;
            *(uint4*)&kt[row * LDQ + c8] = *(const uint4*)(Kb + (size_t)(j0 + row) * DHEAD + c8);
            *(uint4*)&vt[row * LDQ + c8] = *(const uint4*)(Vb + (size_t)row * SEQ + j0 + c8);
        }
        const int base1 = SEQ + j0 - i0 - TQ;
        for (int idx = tid; idx < NW * 8; idx += 256) {
            int l = idx >> 3, c8 = (idx & 7) * 8;
            int rr = base1 + l;
            uint4 val = make_uint4(0, 0, 0, 0);
            if (rr < SEQ)      val = *(const uint4*)(Rb + (size_t)rr * DHEAD + c8);
            else if (rr > SEQ) val = *(const uint4*)(Rb + (size_t)(rr - SEQ - 1) * DHEAD + c8);
            *(uint4*)&uni[l * LDQ + c8] = val;
        }
        __syncthreads();                          // staging visible
        // bias dot-products
        if (tid < 64) {
            float a = 0.f;
#pragma unroll
            for (int c8 = 0; c8 < 8; c8++) {
                bf16x8 kv = *(const bf16x8*)&kt[tid * LDQ + c8 * 8];
#pragma unroll
                for (int e = 0; e < 8; e++) a = fmaf(rwb_s[c8 * 8 + e], (float)kv[e], a);
            }
            acb[tid] = a;
        } else if (tid < 64 + NW) {
            int l = tid - 64;
            float a = 0.f;
#pragma unroll
            for (int c8 = 0; c8 < 8; c8++) {
                bf16x8 rv = *(const bf16x8*)&uni[l * LDQ + c8 * 8];
#pragma unroll
                for (int e = 0; e < 8; e++) a = fmaf(rrb_s[c8 * 8 + e], (float)rv[e], a);
            }
            bdb[l] = a;
        }
        __syncthreads();                          // acb/bdb ready
        // ---- MFMA phase ----
        bf16x8 aq0 = *(const bf16x8*)&qs[(16 * w + l16) * LDQ + quad * 8];
        bf16x8 aq1 = *(const bf16x8*)&qs[(16 * w + l16) * LDQ + 32 + quad * 8];
        f32x4 sac[4];
#pragma unroll
        for (int nt = 0; nt < 4; nt++) {
            bf16x8 b0 = *(const bf16x8*)&kt[(nt * 16 + l16) * LDQ + quad * 8];
            bf16x8 b1 = *(const bf16x8*)&kt[(nt * 16 + l16) * LDQ + 32 + quad * 8];
            f32x4 c; c[0] = 0.f; c[1] = 0.f; c[2] = 0.f; c[3] = 0.f;
            c = __builtin_amdgcn_mfma_f32_16x16x32_bf16(aq0, b0, c, 0, 0, 0);
            c = __builtin_amdgcn_mfma_f32_16x16x32_bf16(aq1, b1, c, 0, 0, 0);
            sac[nt] = c;
        }
        f32x4 bdc[8];
#pragma unroll
        for (int lt = 0; lt < 8; lt++) {
            bf16x8 b0 = *(const bf16x8*)&uni[(lt * 16 + l16) * LDQ + quad * 8];
            bf16x8 b1 = *(const bf16x8*)&uni[(lt * 16 + l16) * LDQ + 32 + quad * 8];
            f32x4 c; c[0] = 0.f; c[1] = 0.f; c[2] = 0.f; c[3] = 0.f;
            c = __builtin_amdgcn_mfma_f32_16x16x32_bf16(aq0, b0, c, 0, 0, 0);
            c = __builtin_amdgcn_mfma_f32_16x16x32_bf16(aq1, b1, c, 0, 0, 0);
            bdc[lt] = c;
        }
        // BD band row 64 (case-2 source for il=63), VALU, result to reg
        float bd64 = 0.f;
        if (w == 0) {
#pragma unroll
            for (int c8 = 0; c8 < 8; c8++) {
                bf16x8 qv = *(const bf16x8*)&qs[64 * LDQ + c8 * 8];
                bf16x8 rv = *(const bf16x8*)&uni[lane * LDQ + c8 * 8];
#pragma unroll
                for (int e = 0; e < 8; e++) bd64 = fmaf((float)qv[e], (float)rv[e], bd64);
            }
            bd64 += bdb[lane];
        }
        __syncthreads();                          // rkc reads done -> overwrite
        // store BD band (bf16, += bdb)
#pragma unroll
        for (int lt = 0; lt < 8; lt++) {
            float bv = bdb[lt * 16 + l16];
#pragma unroll
            for (int r = 0; r < 4; r++) {
                int ip = 16 * w + quad * 4 + r;
                uni[ip * LDB + lt * 16 + l16] = (bf16_t)(bdc[lt][r] + bv);
            }
        }
        if (w == 0) uni[64 * LDB + lane] = (bf16_t)bd64;
        __syncthreads();                          // band visible
        // ---- gather + assemble + online softmax ----
        float sv[4][4];
#pragma unroll
        for (int nt = 0; nt < 4; nt++) {
            float ab = acb[nt * 16 + l16];
#pragma unroll
            for (int r = 0; r < 4; r++) {
                int il = 16 * w + quad * 4 + r;
                int jl = nt * 16 + l16;
                int l = jl + (TQ - 1) - il;
                int rr = base1 + l;
                int ip = il + (rr > SEQ ? 1 : 0);
                float bd = (float)uni[ip * LDB + l];
                sv[nt][r] = (sac[nt][r] + ab + bd) * 0.125f;
            }
        }
#pragma unroll
        for (int r = 0; r < 4; r++) {
            float m = fmaxf(fmaxf(sv[0][r], sv[1][r]), fmaxf(sv[2][r], sv[3][r]));
            m = fmaxf(m, __shfl_xor(m, 1));
            m = fmaxf(m, __shfl_xor(m, 2));
            m = fmaxf(m, __shfl_xor(m, 4));
            m = fmaxf(m, __shfl_xor(m, 8));
            float mnew = fmaxf(mprev[r], m);
            float alpha = __expf(mprev[r] - mnew);
            float s = 0.f;
#pragma unroll
            for (int nt = 0; nt < 4; nt++) {
                sv[nt][r] = __expf(sv[nt][r] - mnew);
                s += sv[nt][r];
            }
            s += __shfl_xor(s, 1); s += __shfl_xor(s, 2);
            s += __shfl_xor(s, 4); s += __shfl_xor(s, 8);
            lsum[r] = lsum[r] * alpha + s;
            mprev[r] = mnew;
#pragma unroll
            for (int nt = 0; nt < 4; nt++) o[nt][r] *= alpha;
        }
        __syncthreads();                          // gather reads done -> P reuse
        bf16_t* pw = uni + w * 16 * LDQ;
#pragma unroll
        for (int nt = 0; nt < 4; nt++)
#pragma unroll
            for (int r = 0; r < 4; r++)
                pw[(quad * 4 + r) * LDQ + nt * 16 + l16] = (bf16_t)sv[nt][r];
        __syncthreads();                          // P visible
        // ---- PV ----
        bf16x8 pa0 = *(const bf16x8*)&pw[l16 * LDQ + quad * 8];
        bf16x8 pa1 = *(const bf16x8*)&pw[l16 * LDQ + 32 + quad * 8];
#pragma unroll
        for (int nt = 0; nt < 4; nt++) {
            bf16x8 vb0 = *(const bf16x8*)&vt[(nt * 16 + l16) * LDQ + quad * 8];
            bf16x8 vb1 = *(const bf16x8*)&vt[(nt * 16 + l16) * LDQ + 32 + quad * 8];
            o[nt] = __builtin_amdgcn_mfma_f32_16x16x32_bf16(pa0, vb0, o[nt], 0, 0, 0);
            o[nt] = __builtin_amdgcn_mfma_f32_16x16x32_bf16(pa1, vb1, o[nt], 0, 0, 0);
        }
    }
    // epilogue: normalize, store [b, s, n*64+d] fp32
    float inv[4];
#pragma unroll
    for (int r = 0; r < 4; r++) inv[r] = 1.f / lsum[r];
#pragma unroll
    for (int nt = 0; nt < 4; nt++)
#pragma unroll
        for (int r = 0; r < 4; r++) {
            int gi = i0 + 16 * w + quad * 4 + r;
            Out[(size_t)(b * SEQ + gi) * HID + n * DHEAD + nt * 16 + l16] = o[nt][r] * inv[r];
        }
}

extern "C" void kernel_launch(void* const* d_in, const int* in_sizes, int n_in,
                              void* d_out, int out_size, void* d_ws, size_t ws_size,
                              hipStream_t stream) {
    const float* hs  = (const float*)d_in[0];
    const float* r   = (const float*)d_in[1];
    const float* rwb = (const float*)d_in[2];
    const float* rrb = (const float*)d_in[3];
    const float* Wq  = (const float*)d_in[4];
    const float* bq  = (const float*)d_in[5];
    const float* Wk  = (const float*)d_in[6];
    const float* bk  = (const float*)d_in[7];
    const float* Wv  = (const float*)d_in[8];
    const float* bv  = (const float*)d_in[9];
    const float* Wr  = (const float*)d_in[10];

    bf16_t* Qh = (bf16_t*)d_ws;
    bf16_t* Kh = Qh + (size_t)BATCH * SEQ * HID;
    bf16_t* Vh = Kh + (size_t)BATCH * SEQ * HID;
    bf16_t* Rh = Vh + (size_t)BATCH * SEQ * HID;

    dim3 blk(256);
    gemm_bias_bf16<<<dim3(HID / 64, (BATCH * SEQ) / 64), blk, 0, stream>>>(hs, Wq, bq, Qh, 0);
    gemm_bias_bf16<<<dim3(HID / 64, (BATCH * SEQ) / 64), blk, 0, stream>>>(hs, Wk, bk, Kh, 0);
    gemm_bias_bf16<<<dim3(HID / 64, (BATCH * SEQ) / 64), blk, 0, stream>>>(hs, Wv, bv, Vh, 1);
    gemm_bias_bf16<<<dim3(HID / 64, SEQ / 64), blk, 0, stream>>>(r, Wr, nullptr, Rh, 0);

    rel_attn_mfma<<<dim3(SEQ / TQ, NHEAD, BATCH), blk, 0, stream>>>(
        Qh, Kh, Vh, Rh, rwb, rrb, (float*)d_out);
}

// Round 3
// 646.297 us; speedup vs baseline: 6.5637x; 1.4956x over previous
//
#include <hip/hip_runtime.h>
#include <math.h>

#define HID   1024
#define NHEAD 16
#define DHEAD 64
#define BATCH 2
#define SEQ   2048

#define TQ 64
#define TK 64
#define NW 127      // TQ+TK-1 rel-shift band width
#define LDQ 72      // padded LDS stride (bf16 elems) for q/k/v/rkc/P
#define LDB 140     // padded LDS stride for BD band

#define KSPLIT 2048 // K' = 2*HID (hi/lo interleaved)

typedef __bf16 bf16_t;
typedef bf16_t bf16x8 __attribute__((ext_vector_type(8)));
typedef bf16_t bf16x4 __attribute__((ext_vector_type(4)));
typedef float  f32x4  __attribute__((ext_vector_type(4)));

__device__ __forceinline__ void load_lds16(const void* g, void* l) {
    __builtin_amdgcn_global_load_lds(
        (const __attribute__((address_space(1))) unsigned int*)g,
        (__attribute__((address_space(3))) unsigned int*)l, 16, 0, 0);
}

__device__ __forceinline__ void split2(float x, bf16_t* hi, bf16_t* lo) {
    bf16_t h = (bf16_t)x;
    *hi = h;
    *lo = (bf16_t)(x - (float)h);
}

// ---------------- prep 1: fp32 [M][1024] -> hi/lo-interleaved bf16 [M][2048]
__global__ __launch_bounds__(256) void split_interleave(
    const float* __restrict__ in, bf16_t* __restrict__ out, int n4)
{
    int g = blockIdx.x * 256 + threadIdx.x;
    if (g >= n4) return;
    float4 v = ((const float4*)in)[g];
    int m = g >> 8, c4 = g & 255;       // 256 float4s per 1024-row
    float xs[4] = {v.x, v.y, v.z, v.w};
    bf16x8 o;
#pragma unroll
    for (int e = 0; e < 4; e++) {
        bf16_t h, l; split2(xs[e], &h, &l);
        o[2 * e] = h; o[2 * e + 1] = l;
    }
    *(bf16x8*)(out + (size_t)m * KSPLIT + c4 * 8) = o;
}

// ---------------- prep 2: W fp32 [1024 k][1024 n] -> Wt' bf16 [1024 n][2048 k']
__global__ __launch_bounds__(256) void transpose_split(
    const float* __restrict__ W, bf16_t* __restrict__ Wt)
{
    __shared__ float t[64][65];
    const int tid = threadIdx.x;
    const int n0 = blockIdx.x * 64, k0 = blockIdx.y * 64;
    for (int idx = tid; idx < 1024; idx += 256) {
        int r = idx >> 4, c4 = (idx & 15) * 4;
        float4 v = *(const float4*)(W + (size_t)(k0 + r) * HID + n0 + c4);
        t[r][c4] = v.x; t[r][c4 + 1] = v.y; t[r][c4 + 2] = v.z; t[r][c4 + 3] = v.w;
    }
    __syncthreads();
    for (int idx = tid; idx < 1024; idx += 256) {
        int nr = idx >> 4, c4 = (idx & 15) * 4;   // k-chunk
        bf16x8 o;
#pragma unroll
        for (int e = 0; e < 4; e++) {
            bf16_t h, l; split2(t[c4 + e][nr], &h, &l);
            o[2 * e] = h; o[2 * e + 1] = l;
        }
        *(bf16x8*)(Wt + (size_t)(n0 + nr) * KSPLIT + (k0 + c4) * 2) = o;
    }
}

// ---------------- split-bf16 MFMA GEMM ---------------------------------------
// C = A[M][2048'] @ Wt'[1024][2048']^T ; fp32-grade accuracy via hi/lo K-interleave.
// 128x128 tile, BK=64, global_load_lds w/ XOR-chunk swizzle.
// vmode 0: C[((b*16+nh)*2048+s)*64+d]  (Q,K,R);  vmode 1: swap operands ->
// C^T computed directly, stores V as [((b*16+nh)*64+d)*2048+s], coalesced in s.
__global__ __launch_bounds__(256, 3) void gemm_split_mfma(
    const bf16_t* __restrict__ A, const bf16_t* __restrict__ Bw,
    const float* __restrict__ bias, bf16_t* __restrict__ C, int M, int vmode)
{
    __shared__ bf16_t As[128 * 64];
    __shared__ bf16_t Bs[128 * 64];
    const int tid = threadIdx.x;
    const int w = tid >> 6, lane = tid & 63;
    const int quad = lane >> 4, l16 = lane & 15;
    const int bn = blockIdx.x * 128;
    const int bm = blockIdx.y * 128;

    // staging constants: slot p = j*256+tid; row r=p>>3; phys chunk p&7;
    // global chunk = (p&7) ^ (r&7)
    const int srow = tid >> 3;                       // + j*32
    const int scg  = (tid & 7) ^ ((tid >> 3) & 7);   // global chunk
    const bf16_t* Ab = A  + (size_t)(bm + srow) * KSPLIT + scg * 8;
    const bf16_t* Bb = Bw + (size_t)(bn + srow) * KSPLIT + scg * 8;

    f32x4 acc[2][8];
#pragma unroll
    for (int i = 0; i < 2; i++)
#pragma unroll
        for (int j = 0; j < 8; j++) {
            acc[i][j][0] = 0.f; acc[i][j][1] = 0.f;
            acc[i][j][2] = 0.f; acc[i][j][3] = 0.f;
        }

    const bf16_t* P1 = (vmode == 1) ? Bs : As;   // A-operand (wave-owned rows)
    const bf16_t* P2 = (vmode == 1) ? As : Bs;   // B-operand (all 128 rows)

    for (int k0 = 0; k0 < KSPLIT; k0 += 64) {
#pragma unroll
        for (int j = 0; j < 4; j++) {
            load_lds16(Ab + (size_t)j * 32 * KSPLIT + k0, &As[j * 2048 + w * 512]);
            load_lds16(Bb + (size_t)j * 32 * KSPLIT + k0, &Bs[j * 2048 + w * 512]);
        }
        __syncthreads();

        bf16x8 af[2][2];
#pragma unroll
        for (int mt = 0; mt < 2; mt++) {
            int r = w * 32 + mt * 16 + l16, rx = r & 7;
            int c0 = (quad ^ rx);
            af[mt][0] = *(const bf16x8*)&P1[r * 64 + c0 * 8];
            af[mt][1] = *(const bf16x8*)&P1[r * 64 + (c0 ^ 4) * 8];
        }
#pragma unroll
        for (int nt = 0; nt < 8; nt++) {
            int r = nt * 16 + l16, rx = r & 7;
            int c0 = (quad ^ rx);
            bf16x8 b0 = *(const bf16x8*)&P2[r * 64 + c0 * 8];
            bf16x8 b1 = *(const bf16x8*)&P2[r * 64 + (c0 ^ 4) * 8];
#pragma unroll
            for (int mt = 0; mt < 2; mt++) {
                acc[mt][nt] = __builtin_amdgcn_mfma_f32_16x16x32_bf16(af[mt][0], b0, acc[mt][nt], 0, 0, 0);
                acc[mt][nt] = __builtin_amdgcn_mfma_f32_16x16x32_bf16(af[mt][1], b1, acc[mt][nt], 0, 0, 0);
            }
        }
        __syncthreads();
    }

    // epilogue
#pragma unroll
    for (int mt = 0; mt < 2; mt++)
#pragma unroll
        for (int nt = 0; nt < 8; nt++)
#pragma unroll
            for (int r4 = 0; r4 < 4; r4++) {
                int rowp = w * 32 + mt * 16 + quad * 4 + r4;
                int colp = nt * 16 + l16;
                float v = acc[mt][nt][r4];
                if (vmode == 0) {
                    int m = bm + rowp, n = bn + colp;
                    if (bias) v += bias[n];
                    int bb = m >> 11, s = m & (SEQ - 1);
                    int nh = n >> 6, d = n & 63;
                    C[(((size_t)(bb * NHEAD + nh) * SEQ + s) * DHEAD) + d] = (bf16_t)v;
                } else {
                    int n = bn + rowp, m = bm + colp;
                    if (bias) v += bias[n];
                    int bb = m >> 11, s = m & (SEQ - 1);
                    int nh = n >> 6, d = n & 63;
                    C[(((size_t)(bb * NHEAD + nh) * DHEAD + d) * SEQ) + s] = (bf16_t)v;
                }
            }
}

// ---------------- MFMA flash rel-attention (unchanged from round 2) ----------
__global__ __launch_bounds__(256, 3) void rel_attn_mfma(
    const bf16_t* __restrict__ Qh, const bf16_t* __restrict__ Kh,
    const bf16_t* __restrict__ Vth, const bf16_t* __restrict__ Rkh,
    const float* __restrict__ rwb, const float* __restrict__ rrb,
    float* __restrict__ Out)
{
    __shared__ bf16_t qs[65 * LDQ];
    __shared__ bf16_t kt[64 * LDQ];
    __shared__ bf16_t vt[64 * LDQ];          // [d][key]
    __shared__ bf16_t uni[128 * LDQ];        // union: rkc | BDband | P
    __shared__ float acb[64];
    __shared__ float bdb[128];
    __shared__ float rwb_s[64], rrb_s[64];

    const int tid = threadIdx.x;
    const int w = tid >> 6, lane = tid & 63;
    const int quad = lane >> 4, l16 = lane & 15;
    const int i0 = blockIdx.x * TQ;
    const int n = blockIdx.y, b = blockIdx.z;

    const bf16_t* Qb = Qh + ((size_t)(b * NHEAD + n) * SEQ + i0) * DHEAD;
    const bf16_t* Kb = Kh + (size_t)(b * NHEAD + n) * SEQ * DHEAD;
    const bf16_t* Vb = Vth + (size_t)(b * NHEAD + n) * DHEAD * SEQ;
    const bf16_t* Rb = Rkh + (size_t)n * SEQ * DHEAD;

    for (int idx = tid; idx < 65 * 8; idx += 256) {
        int row = idx >> 3, c8 = (idx & 7) * 8;
        uint4 val = make_uint4(0, 0, 0, 0);
        if (i0 + row < SEQ) val = *(const uint4*)(Qb + row * DHEAD + c8);
        *(uint4*)&qs[row * LDQ + c8] = val;
    }
    if (tid < 64) rwb_s[tid] = rwb[n * DHEAD + tid];
    else if (tid < 128) rrb_s[tid - 64] = rrb[n * DHEAD + tid - 64];

    f32x4 o[4];
    float mprev[4], lsum[4];
#pragma unroll
    for (int t = 0; t < 4; t++) {
        o[t][0] = 0.f; o[t][1] = 0.f; o[t][2] = 0.f; o[t][3] = 0.f;
        mprev[t] = -3.0e38f; lsum[t] = 0.f;
    }

    for (int j0 = 0; j0 < SEQ; j0 += TK) {
        __syncthreads();
        for (int idx = tid; idx < 64 * 8; idx += 256) {
            int row = idx >> 3, c8 = (idx & 7) * 8;
            *(uint4*)&kt[row * LDQ + c8] = *(const uint4*)(Kb + (size_t)(j0 + row) * DHEAD + c8);
            *(uint4*)&vt[row * LDQ + c8] = *(const uint4*)(Vb + (size_t)row * SEQ + j0 + c8);
        }
        const int base1 = SEQ + j0 - i0 - TQ;
        for (int idx = tid; idx < NW * 8; idx += 256) {
            int l = idx >> 3, c8 = (idx & 7) * 8;
            int rr = base1 + l;
            uint4 val = make_uint4(0, 0, 0, 0);
            if (rr < SEQ)      val = *(const uint4*)(Rb + (size_t)rr * DHEAD + c8);
            else if (rr > SEQ) val = *(const uint4*)(Rb + (size_t)(rr - SEQ - 1) * DHEAD + c8);
            *(uint4*)&uni[l * LDQ + c8] = val;
        }
        __syncthreads();
        if (tid < 64) {
            float a = 0.f;
#pragma unroll
            for (int c8 = 0; c8 < 8; c8++) {
                bf16x8 kv = *(const bf16x8*)&kt[tid * LDQ + c8 * 8];
#pragma unroll
                for (int e = 0; e < 8; e++) a = fmaf(rwb_s[c8 * 8 + e], (float)kv[e], a);
            }
            acb[tid] = a;
        } else if (tid < 64 + NW) {
            int l = tid - 64;
            float a = 0.f;
#pragma unroll
            for (int c8 = 0; c8 < 8; c8++) {
                bf16x8 rv = *(const bf16x8*)&uni[l * LDQ + c8 * 8];
#pragma unroll
                for (int e = 0; e < 8; e++) a = fmaf(rrb_s[c8 * 8 + e], (float)rv[e], a);
            }
            bdb[l] = a;
        }
        __syncthreads();
        bf16x8 aq0 = *(const bf16x8*)&qs[(16 * w + l16) * LDQ + quad * 8];
        bf16x8 aq1 = *(const bf16x8*)&qs[(16 * w + l16) * LDQ + 32 + quad * 8];
        f32x4 sac[4];
#pragma unroll
        for (int nt = 0; nt < 4; nt++) {
            bf16x8 b0 = *(const bf16x8*)&kt[(nt * 16 + l16) * LDQ + quad * 8];
            bf16x8 b1 = *(const bf16x8*)&kt[(nt * 16 + l16) * LDQ + 32 + quad * 8];
            f32x4 c; c[0] = 0.f; c[1] = 0.f; c[2] = 0.f; c[3] = 0.f;
            c = __builtin_amdgcn_mfma_f32_16x16x32_bf16(aq0, b0, c, 0, 0, 0);
            c = __builtin_amdgcn_mfma_f32_16x16x32_bf16(aq1, b1, c, 0, 0, 0);
            sac[nt] = c;
        }
        f32x4 bdc[8];
#pragma unroll
        for (int lt = 0; lt < 8; lt++) {
            bf16x8 b0 = *(const bf16x8*)&uni[(lt * 16 + l16) * LDQ + quad * 8];
            bf16x8 b1 = *(const bf16x8*)&uni[(lt * 16 + l16) * LDQ + 32 + quad * 8];
            f32x4 c; c[0] = 0.f; c[1] = 0.f; c[2] = 0.f; c[3] = 0.f;
            c = __builtin_amdgcn_mfma_f32_16x16x32_bf16(aq0, b0, c, 0, 0, 0);
            c = __builtin_amdgcn_mfma_f32_16x16x32_bf16(aq1, b1, c, 0, 0, 0);
            bdc[lt] = c;
        }
        float bd64 = 0.f;
        if (w == 0) {
#pragma unroll
            for (int c8 = 0; c8 < 8; c8++) {
                bf16x8 qv = *(const bf16x8*)&qs[64 * LDQ + c8 * 8];
                bf16x8 rv = *(const bf16x8*)&uni[lane * LDQ + c8 * 8];
#pragma unroll
                for (int e = 0; e < 8; e++) bd64 = fmaf((float)qv[e], (float)rv[e], bd64);
            }
            bd64 += bdb[lane];
        }
        __syncthreads();
#pragma unroll
        for (int lt = 0; lt < 8; lt++) {
            float bv = bdb[lt * 16 + l16];
#pragma unroll
            for (int r = 0; r < 4; r++) {
                int ip = 16 * w + quad * 4 + r;
                uni[ip * LDB + lt * 16 + l16] = (bf16_t)(bdc[lt][r] + bv);
            }
        }
        if (w == 0) uni[64 * LDB + lane] = (bf16_t)bd64;
        __syncthreads();
        float sv[4][4];
#pragma unroll
        for (int nt = 0; nt < 4; nt++) {
            float ab = acb[nt * 16 + l16];
#pragma unroll
            for (int r = 0; r < 4; r++) {
                int il = 16 * w + quad * 4 + r;
                int jl = nt * 16 + l16;
                int l = jl + (TQ - 1) - il;
                int rr = base1 + l;
                int ip = il + (rr > SEQ ? 1 : 0);
                float bd = (float)uni[ip * LDB + l];
                sv[nt][r] = (sac[nt][r] + ab + bd) * 0.125f;
            }
        }
#pragma unroll
        for (int r = 0; r < 4; r++) {
            float m = fmaxf(fmaxf(sv[0][r], sv[1][r]), fmaxf(sv[2][r], sv[3][r]));
            m = fmaxf(m, __shfl_xor(m, 1));
            m = fmaxf(m, __shfl_xor(m, 2));
            m = fmaxf(m, __shfl_xor(m, 4));
            m = fmaxf(m, __shfl_xor(m, 8));
            float mnew = fmaxf(mprev[r], m);
            float alpha = __expf(mprev[r] - mnew);
            float s = 0.f;
#pragma unroll
            for (int nt = 0; nt < 4; nt++) {
                sv[nt][r] = __expf(sv[nt][r] - mnew);
                s += sv[nt][r];
            }
            s += __shfl_xor(s, 1); s += __shfl_xor(s, 2);
            s += __shfl_xor(s, 4); s += __shfl_xor(s, 8);
            lsum[r] = lsum[r] * alpha + s;
            mprev[r] = mnew;
#pragma unroll
            for (int nt = 0; nt < 4; nt++) o[nt][r] *= alpha;
        }
        __syncthreads();
        bf16_t* pw = uni + w * 16 * LDQ;
#pragma unroll
        for (int nt = 0; nt < 4; nt++)
#pragma unroll
            for (int r = 0; r < 4; r++)
                pw[(quad * 4 + r) * LDQ + nt * 16 + l16] = (bf16_t)sv[nt][r];
        __syncthreads();
        bf16x8 pa0 = *(const bf16x8*)&pw[l16 * LDQ + quad * 8];
        bf16x8 pa1 = *(const bf16x8*)&pw[l16 * LDQ + 32 + quad * 8];
#pragma unroll
        for (int nt = 0; nt < 4; nt++) {
            bf16x8 vb0 = *(const bf16x8*)&vt[(nt * 16 + l16) * LDQ + quad * 8];
            bf16x8 vb1 = *(const bf16x8*)&vt[(nt * 16 + l16) * LDQ + 32 + quad * 8];
            o[nt] = __builtin_amdgcn_mfma_f32_16x16x32_bf16(pa0, vb0, o[nt], 0, 0, 0);
            o[nt] = __builtin_amdgcn_mfma_f32_16x16x32_bf16(pa1, vb1, o[nt], 0, 0, 0);
        }
    }
    float inv[4];
#pragma unroll
    for (int r = 0; r < 4; r++) inv[r] = 1.f / lsum[r];
#pragma unroll
    for (int nt = 0; nt < 4; nt++)
#pragma unroll
        for (int r = 0; r < 4; r++) {
            int gi = i0 + 16 * w + quad * 4 + r;
            Out[(size_t)(b * SEQ + gi) * HID + n * DHEAD + nt * 16 + l16] = o[nt][r] * inv[r];
        }
}

extern "C" void kernel_launch(void* const* d_in, const int* in_sizes, int n_in,
                              void* d_out, int out_size, void* d_ws, size_t ws_size,
                              hipStream_t stream) {
    const float* hs  = (const float*)d_in[0];
    const float* r   = (const float*)d_in[1];
    const float* rwb = (const float*)d_in[2];
    const float* rrb = (const float*)d_in[3];
    const float* Wq  = (const float*)d_in[4];
    const float* bq  = (const float*)d_in[5];
    const float* Wk  = (const float*)d_in[6];
    const float* bk  = (const float*)d_in[7];
    const float* Wv  = (const float*)d_in[8];
    const float* bv  = (const float*)d_in[9];
    const float* Wr  = (const float*)d_in[10];

    // workspace (bf16 elems), total exactly 58,720,256 bytes:
    bf16_t* ws0 = (bf16_t*)d_ws;
    bf16_t* hsS = ws0;                         // [4096][2048]   16.78 MB
    bf16_t* rS  = hsS + (size_t)4096 * KSPLIT; // [2048][2048]    8.39 MB
    bf16_t* WtS = rS  + (size_t)2048 * KSPLIT; // [1024][2048]    4.19 MB (serial reuse)
    bf16_t* Qh  = WtS + (size_t)1024 * KSPLIT;
    bf16_t* Kh  = Qh + (size_t)BATCH * SEQ * HID;
    bf16_t* Vh  = Kh + (size_t)BATCH * SEQ * HID;
    bf16_t* Rh  = Vh + (size_t)BATCH * SEQ * HID;

    dim3 blk(256);
    // prep: split-interleave activations
    split_interleave<<<4096, blk, 0, stream>>>(hs, hsS, (BATCH * SEQ * HID) / 4);
    split_interleave<<<2048, blk, 0, stream>>>(r, rS, (SEQ * HID) / 4);

    dim3 g_t(16, 16);
    // Q
    transpose_split<<<g_t, blk, 0, stream>>>(Wq, WtS);
    gemm_split_mfma<<<dim3(8, 32), blk, 0, stream>>>(hsS, WtS, bq, Qh, BATCH * SEQ, 0);
    // K
    transpose_split<<<g_t, blk, 0, stream>>>(Wk, WtS);
    gemm_split_mfma<<<dim3(8, 32), blk, 0, stream>>>(hsS, WtS, bk, Kh, BATCH * SEQ, 0);
    // V (swap-mode: writes transposed [d][s] layout directly)
    transpose_split<<<g_t, blk, 0, stream>>>(Wv, WtS);
    gemm_split_mfma<<<dim3(8, 32), blk, 0, stream>>>(hsS, WtS, bv, Vh, BATCH * SEQ, 1);
    // R
    transpose_split<<<g_t, blk, 0, stream>>>(Wr, WtS);
    gemm_split_mfma<<<dim3(8, 16), blk, 0, stream>>>(rS, WtS, nullptr, Rh, SEQ, 0);

    rel_attn_mfma<<<dim3(SEQ / TQ, NHEAD, BATCH), blk, 0, stream>>>(
        Qh, Kh, Vh, Rh, rwb, rrb, (float*)d_out);
}

// Round 4
// 496.784 us; speedup vs baseline: 8.5391x; 1.3010x over previous
//
#include <hip/hip_runtime.h>
#include <math.h>

#define HID   1024
#define NHEAD 16
#define DHEAD 64
#define BATCH 2
#define SEQ   2048

#define TQ   64
#define TK2  128
#define NW2  191     // TQ+TK2-1 rel-shift band rows
#define LDQ  72      // padded LDS stride (bf16) for q/k/rkc
#define LDV  136     // padded stride for vt / P (128 + 8)
#define LDB2 198     // padded stride for BD band (192 + 6)

#define KSPLIT 2048  // K' = 2*HID (hi/lo interleaved)
#define HEADSZ ((size_t)BATCH * SEQ * HID)   // 4,194,304 bf16 elems per Q/K/V buf

typedef __bf16 bf16_t;
typedef bf16_t bf16x8 __attribute__((ext_vector_type(8)));
typedef bf16_t bf16x4 __attribute__((ext_vector_type(4)));
typedef float  f32x4  __attribute__((ext_vector_type(4)));

__device__ __forceinline__ void load_lds16(const void* g, void* l) {
    __builtin_amdgcn_global_load_lds(
        (const __attribute__((address_space(1))) unsigned int*)g,
        (__attribute__((address_space(3))) unsigned int*)l, 16, 0, 0);
}

__device__ __forceinline__ void split2(float x, bf16_t* hi, bf16_t* lo) {
    bf16_t h = (bf16_t)x;
    *hi = h;
    *lo = (bf16_t)(x - (float)h);
}

// ---------------- prep 1: fp32 [M][1024] -> hi/lo-interleaved bf16 [M][2048]
__global__ __launch_bounds__(256) void split_interleave(
    const float* __restrict__ in, bf16_t* __restrict__ out, int n4)
{
    int g = blockIdx.x * 256 + threadIdx.x;
    if (g >= n4) return;
    float4 v = ((const float4*)in)[g];
    int m = g >> 8, c4 = g & 255;
    float xs[4] = {v.x, v.y, v.z, v.w};
    bf16x8 o;
#pragma unroll
    for (int e = 0; e < 4; e++) {
        bf16_t h, l; split2(xs[e], &h, &l);
        o[2 * e] = h; o[2 * e + 1] = l;
    }
    *(bf16x8*)(out + (size_t)m * KSPLIT + c4 * 8) = o;
}

// ---------------- prep 2: W fp32 [1024 k][1024 n] -> Wt' bf16 [1024 n][2048 k']
__global__ __launch_bounds__(256) void transpose_split(
    const float* __restrict__ W, bf16_t* __restrict__ Wt)
{
    __shared__ float t[64][65];
    const int tid = threadIdx.x;
    const int n0 = blockIdx.x * 64, k0 = blockIdx.y * 64;
    for (int idx = tid; idx < 1024; idx += 256) {
        int r = idx >> 4, c4 = (idx & 15) * 4;
        float4 v = *(const float4*)(W + (size_t)(k0 + r) * HID + n0 + c4);
        t[r][c4] = v.x; t[r][c4 + 1] = v.y; t[r][c4 + 2] = v.z; t[r][c4 + 3] = v.w;
    }
    __syncthreads();
    for (int idx = tid; idx < 1024; idx += 256) {
        int nr = idx >> 4, c4 = (idx & 15) * 4;
        bf16x8 o;
#pragma unroll
        for (int e = 0; e < 4; e++) {
            bf16_t h, l; split2(t[c4 + e][nr], &h, &l);
            o[2 * e] = h; o[2 * e + 1] = l;
        }
        *(bf16x8*)(Wt + (size_t)(n0 + nr) * KSPLIT + (k0 + c4) * 2) = o;
    }
}

// ---------------- fused QKV split-bf16 MFMA GEMM ----------------------------
// A[4096][2048'] @ Wt3[3072][2048']^T. proj = bn>>10: 0=Q,1=K (row layout),
// 2=V (operand swap -> transposed [d][s] layout directly).
__global__ __launch_bounds__(256, 3) void gemm_qkv_fused(
    const bf16_t* __restrict__ A, const bf16_t* __restrict__ Wt3,
    const float* __restrict__ bq, const float* __restrict__ bk,
    const float* __restrict__ bv, bf16_t* __restrict__ Cq)
{
    __shared__ bf16_t As[128 * 64];
    __shared__ bf16_t Bs[128 * 64];
    const int tid = threadIdx.x;
    const int w = tid >> 6, lane = tid & 63;
    const int quad = lane >> 4, l16 = lane & 15;
    const int bn = blockIdx.x * 128;
    const int bm = blockIdx.y * 128;
    const int proj = bn >> 10;
    const int vswap = (proj == 2);

    const int srow = tid >> 3;
    const int scg  = (tid & 7) ^ ((tid >> 3) & 7);
    const bf16_t* Ab = A   + (size_t)(bm + srow) * KSPLIT + scg * 8;
    const bf16_t* Bb = Wt3 + (size_t)(bn + srow) * KSPLIT + scg * 8;

    f32x4 acc[2][8];
#pragma unroll
    for (int i = 0; i < 2; i++)
#pragma unroll
        for (int j = 0; j < 8; j++) {
            acc[i][j][0] = 0.f; acc[i][j][1] = 0.f;
            acc[i][j][2] = 0.f; acc[i][j][3] = 0.f;
        }

    const bf16_t* P1 = vswap ? Bs : As;
    const bf16_t* P2 = vswap ? As : Bs;

    for (int k0 = 0; k0 < KSPLIT; k0 += 64) {
#pragma unroll
        for (int j = 0; j < 4; j++) {
            load_lds16(Ab + (size_t)j * 32 * KSPLIT + k0, &As[j * 2048 + w * 512]);
            load_lds16(Bb + (size_t)j * 32 * KSPLIT + k0, &Bs[j * 2048 + w * 512]);
        }
        __syncthreads();
        bf16x8 af[2][2];
#pragma unroll
        for (int mt = 0; mt < 2; mt++) {
            int r = w * 32 + mt * 16 + l16, rx = r & 7;
            int c0 = (quad ^ rx);
            af[mt][0] = *(const bf16x8*)&P1[r * 64 + c0 * 8];
            af[mt][1] = *(const bf16x8*)&P1[r * 64 + (c0 ^ 4) * 8];
        }
#pragma unroll
        for (int nt = 0; nt < 8; nt++) {
            int r = nt * 16 + l16, rx = r & 7;
            int c0 = (quad ^ rx);
            bf16x8 b0 = *(const bf16x8*)&P2[r * 64 + c0 * 8];
            bf16x8 b1 = *(const bf16x8*)&P2[r * 64 + (c0 ^ 4) * 8];
#pragma unroll
            for (int mt = 0; mt < 2; mt++) {
                acc[mt][nt] = __builtin_amdgcn_mfma_f32_16x16x32_bf16(af[mt][0], b0, acc[mt][nt], 0, 0, 0);
                acc[mt][nt] = __builtin_amdgcn_mfma_f32_16x16x32_bf16(af[mt][1], b1, acc[mt][nt], 0, 0, 0);
            }
        }
        __syncthreads();
    }

#pragma unroll
    for (int mt = 0; mt < 2; mt++)
#pragma unroll
        for (int nt = 0; nt < 8; nt++)
#pragma unroll
            for (int r4 = 0; r4 < 4; r4++) {
                int rowp = w * 32 + mt * 16 + quad * 4 + r4;
                int colp = nt * 16 + l16;
                float v = acc[mt][nt][r4];
                if (!vswap) {
                    int m = bm + rowp, nloc = (bn & 1023) + colp;
                    v += (proj == 0) ? bq[nloc] : bk[nloc];
                    int bb = m >> 11, s = m & (SEQ - 1);
                    int nh = nloc >> 6, d = nloc & 63;
                    Cq[(size_t)proj * HEADSZ + (((size_t)(bb * NHEAD + nh) * SEQ + s) * DHEAD) + d] = (bf16_t)v;
                } else {
                    int nloc = (bn & 1023) + rowp, m = bm + colp;
                    v += bv[nloc];
                    int bb = m >> 11, s = m & (SEQ - 1);
                    int nh = nloc >> 6, d = nloc & 63;
                    Cq[(size_t)2 * HEADSZ + (((size_t)(bb * NHEAD + nh) * DHEAD + d) * SEQ) + s] = (bf16_t)v;
                }
            }
}

// ---------------- R projection (single, row layout) -------------------------
__global__ __launch_bounds__(256, 3) void gemm_split_mfma(
    const bf16_t* __restrict__ A, const bf16_t* __restrict__ Bw,
    bf16_t* __restrict__ C)
{
    __shared__ bf16_t As[128 * 64];
    __shared__ bf16_t Bs[128 * 64];
    const int tid = threadIdx.x;
    const int w = tid >> 6, lane = tid & 63;
    const int quad = lane >> 4, l16 = lane & 15;
    const int bn = blockIdx.x * 128;
    const int bm = blockIdx.y * 128;
    const int srow = tid >> 3;
    const int scg  = (tid & 7) ^ ((tid >> 3) & 7);
    const bf16_t* Ab = A  + (size_t)(bm + srow) * KSPLIT + scg * 8;
    const bf16_t* Bb = Bw + (size_t)(bn + srow) * KSPLIT + scg * 8;

    f32x4 acc[2][8];
#pragma unroll
    for (int i = 0; i < 2; i++)
#pragma unroll
        for (int j = 0; j < 8; j++) {
            acc[i][j][0] = 0.f; acc[i][j][1] = 0.f;
            acc[i][j][2] = 0.f; acc[i][j][3] = 0.f;
        }

    for (int k0 = 0; k0 < KSPLIT; k0 += 64) {
#pragma unroll
        for (int j = 0; j < 4; j++) {
            load_lds16(Ab + (size_t)j * 32 * KSPLIT + k0, &As[j * 2048 + w * 512]);
            load_lds16(Bb + (size_t)j * 32 * KSPLIT + k0, &Bs[j * 2048 + w * 512]);
        }
        __syncthreads();
        bf16x8 af[2][2];
#pragma unroll
        for (int mt = 0; mt < 2; mt++) {
            int r = w * 32 + mt * 16 + l16, rx = r & 7;
            int c0 = (quad ^ rx);
            af[mt][0] = *(const bf16x8*)&As[r * 64 + c0 * 8];
            af[mt][1] = *(const bf16x8*)&As[r * 64 + (c0 ^ 4) * 8];
        }
#pragma unroll
        for (int nt = 0; nt < 8; nt++) {
            int r = nt * 16 + l16, rx = r & 7;
            int c0 = (quad ^ rx);
            bf16x8 b0 = *(const bf16x8*)&Bs[r * 64 + c0 * 8];
            bf16x8 b1 = *(const bf16x8*)&Bs[r * 64 + (c0 ^ 4) * 8];
#pragma unroll
            for (int mt = 0; mt < 2; mt++) {
                acc[mt][nt] = __builtin_amdgcn_mfma_f32_16x16x32_bf16(af[mt][0], b0, acc[mt][nt], 0, 0, 0);
                acc[mt][nt] = __builtin_amdgcn_mfma_f32_16x16x32_bf16(af[mt][1], b1, acc[mt][nt], 0, 0, 0);
            }
        }
        __syncthreads();
    }
#pragma unroll
    for (int mt = 0; mt < 2; mt++)
#pragma unroll
        for (int nt = 0; nt < 8; nt++)
#pragma unroll
            for (int r4 = 0; r4 < 4; r4++) {
                int rowp = w * 32 + mt * 16 + quad * 4 + r4;
                int colp = nt * 16 + l16;
                int s = bm + rowp, n = bn + colp;
                int nh = n >> 6, d = n & 63;
                C[(((size_t)nh * SEQ + s) * DHEAD) + d] = (bf16_t)acc[mt][nt][r4];
            }
}

// ---------------- prep 3: dcorr[b,n,s] = (rwb-rrb) . K[b,n,s,:] -------------
__global__ __launch_bounds__(256) void dcorr_kernel(
    const bf16_t* __restrict__ Kh, const float* __restrict__ rwb,
    const float* __restrict__ rrb, float* __restrict__ dc)
{
    int g = blockIdx.x * 256 + threadIdx.x;   // < 2*16*2048
    int bn = g >> 11;
    int n = bn & (NHEAD - 1);
    const bf16_t* kr = Kh + (size_t)g * DHEAD;
    float a = 0.f;
#pragma unroll
    for (int c8 = 0; c8 < 8; c8++) {
        bf16x8 kv = *(const bf16x8*)(kr + c8 * 8);
#pragma unroll
        for (int e = 0; e < 8; e++) {
            int d = c8 * 8 + e;
            a = fmaf(rwb[n * DHEAD + d] - rrb[n * DHEAD + d], (float)kv[e], a);
        }
    }
    dc[g] = a;
}

// ---------------- MFMA flash rel-attention, TK=128, biases folded -----------
// qs = q + rrb. AC = qs.K^T (+ dcorr[j] corrects to rwb). Band = qs.rkc^T
// (rrb included). 6 barriers / 128 cols.
__global__ __launch_bounds__(256, 2) void rel_attn_mfma2(
    const bf16_t* __restrict__ Qh, const bf16_t* __restrict__ Kh,
    const bf16_t* __restrict__ Vth, const bf16_t* __restrict__ Rkh,
    const float* __restrict__ rrb, const float* __restrict__ dcorr,
    float* __restrict__ Out)
{
    __shared__ bf16_t qs[65 * LDQ];          // q + rrb, rows i0..i0+64
    __shared__ bf16_t kt[TK2 * LDQ];
    __shared__ bf16_t vt[DHEAD * LDV];       // [d][key]
    __shared__ bf16_t uni[192 * LDQ];        // rkc(191x72) U band(65x198) U P(64x136)
    __shared__ float dco[TK2];

    const int tid = threadIdx.x;
    const int w = tid >> 6, lane = tid & 63;
    const int quad = lane >> 4, l16 = lane & 15;
    const int i0 = blockIdx.x * TQ;
    const int n = blockIdx.y, b = blockIdx.z;

    const bf16_t* Qb = Qh + ((size_t)(b * NHEAD + n) * SEQ + i0) * DHEAD;
    const bf16_t* Kb = Kh + (size_t)(b * NHEAD + n) * SEQ * DHEAD;
    const bf16_t* Vb = Vth + (size_t)(b * NHEAD + n) * DHEAD * SEQ;
    const bf16_t* Rb = Rkh + (size_t)n * SEQ * DHEAD;
    const float*  Db = dcorr + (size_t)(b * NHEAD + n) * SEQ;

    // block-start: stage q+rrb rows i0..i0+64 (row 64 may be OOB -> 0)
    {
        int c8 = (tid & 7) * 8;
        float rv[8];
#pragma unroll
        for (int e = 0; e < 8; e++) rv[e] = rrb[n * DHEAD + c8 + e];
        for (int idx = tid; idx < 65 * 8; idx += 256) {
            int row = idx >> 3;
            uint4 val = make_uint4(0, 0, 0, 0);
            if (i0 + row < SEQ) val = *(const uint4*)(Qb + row * DHEAD + c8);
            bf16x8 q8 = *(bf16x8*)&val;
            bf16x8 o8;
#pragma unroll
            for (int e = 0; e < 8; e++) o8[e] = (bf16_t)((float)q8[e] + rv[e]);
            *(bf16x8*)&qs[row * LDQ + c8] = o8;
        }
    }

    f32x4 o[4];
    float mprev[4], lsum[4];
#pragma unroll
    for (int t = 0; t < 4; t++) {
        o[t][0] = 0.f; o[t][1] = 0.f; o[t][2] = 0.f; o[t][3] = 0.f;
        mprev[t] = -3.0e38f; lsum[t] = 0.f;
    }

    for (int j0 = 0; j0 < SEQ; j0 += TK2) {
        __syncthreads();                             // B1: prev consumers done
        for (int idx = tid; idx < TK2 * 8; idx += 256) {
            int row = idx >> 3, c8 = (idx & 7) * 8;
            *(uint4*)&kt[row * LDQ + c8] = *(const uint4*)(Kb + (size_t)(j0 + row) * DHEAD + c8);
        }
        for (int idx = tid; idx < DHEAD * 16; idx += 256) {
            int d = idx >> 4, kc = (idx & 15) * 8;
            *(uint4*)&vt[d * LDV + kc] = *(const uint4*)(Vb + (size_t)d * SEQ + j0 + kc);
        }
        const int base1 = SEQ + j0 - i0 - TQ;
        for (int idx = tid; idx < NW2 * 8; idx += 256) {
            int l = idx >> 3, c8 = (idx & 7) * 8;
            int rr = base1 + l;
            uint4 val = make_uint4(0, 0, 0, 0);
            if (rr < SEQ)      val = *(const uint4*)(Rb + (size_t)rr * DHEAD + c8);
            else if (rr > SEQ) val = *(const uint4*)(Rb + (size_t)(rr - SEQ - 1) * DHEAD + c8);
            *(uint4*)&uni[l * LDQ + c8] = val;
        }
        if (tid < TK2) dco[tid] = Db[j0 + tid];
        __syncthreads();                             // B2: staging visible

        // ---- MFMA: AC (8x2) + BD band (12x2) ----
        bf16x8 aq0 = *(const bf16x8*)&qs[(16 * w + l16) * LDQ + quad * 8];
        bf16x8 aq1 = *(const bf16x8*)&qs[(16 * w + l16) * LDQ + 32 + quad * 8];
        f32x4 sac[8];
#pragma unroll
        for (int nt = 0; nt < 8; nt++) {
            bf16x8 b0 = *(const bf16x8*)&kt[(nt * 16 + l16) * LDQ + quad * 8];
            bf16x8 b1 = *(const bf16x8*)&kt[(nt * 16 + l16) * LDQ + 32 + quad * 8];
            f32x4 c; c[0] = 0.f; c[1] = 0.f; c[2] = 0.f; c[3] = 0.f;
            c = __builtin_amdgcn_mfma_f32_16x16x32_bf16(aq0, b0, c, 0, 0, 0);
            c = __builtin_amdgcn_mfma_f32_16x16x32_bf16(aq1, b1, c, 0, 0, 0);
            sac[nt] = c;
        }
        f32x4 bdc[12];
#pragma unroll
        for (int lt = 0; lt < 12; lt++) {
            bf16x8 b0 = *(const bf16x8*)&uni[(lt * 16 + l16) * LDQ + quad * 8];
            bf16x8 b1 = *(const bf16x8*)&uni[(lt * 16 + l16) * LDQ + 32 + quad * 8];
            f32x4 c; c[0] = 0.f; c[1] = 0.f; c[2] = 0.f; c[3] = 0.f;
            c = __builtin_amdgcn_mfma_f32_16x16x32_bf16(aq0, b0, c, 0, 0, 0);
            c = __builtin_amdgcn_mfma_f32_16x16x32_bf16(aq1, b1, c, 0, 0, 0);
            bdc[lt] = c;
        }
        // band row 64 (case-2 for il=63): waves 0,1 cover cols 0..127
        float bd64 = 0.f;
        if (w < 2) {
            int l = w * 64 + lane;
#pragma unroll
            for (int c8 = 0; c8 < 8; c8++) {
                bf16x8 qv = *(const bf16x8*)&qs[64 * LDQ + c8 * 8];
                bf16x8 rv = *(const bf16x8*)&uni[l * LDQ + c8 * 8];
#pragma unroll
                for (int e = 0; e < 8; e++) bd64 = fmaf((float)qv[e], (float)rv[e], bd64);
            }
        }
        __syncthreads();                             // B3: rkc reads done
#pragma unroll
        for (int lt = 0; lt < 12; lt++)
#pragma unroll
            for (int r = 0; r < 4; r++) {
                int ip = 16 * w + quad * 4 + r;
                uni[ip * LDB2 + lt * 16 + l16] = (bf16_t)bdc[lt][r];
            }
        if (w < 2) uni[64 * LDB2 + w * 64 + lane] = (bf16_t)bd64;
        __syncthreads();                             // B4: band visible

        // ---- gather + assemble + online softmax ----
        float sv[8][4];
#pragma unroll
        for (int nt = 0; nt < 8; nt++) {
            float dcv = dco[nt * 16 + l16];
#pragma unroll
            for (int r = 0; r < 4; r++) {
                int il = 16 * w + quad * 4 + r;
                int jl = nt * 16 + l16;
                int l = jl + (TQ - 1) - il;
                int rr = base1 + l;
                int ip = il + (rr > SEQ ? 1 : 0);
                float bd = (float)uni[ip * LDB2 + l];
                sv[nt][r] = (sac[nt][r] + dcv + bd) * 0.125f;
            }
        }
#pragma unroll
        for (int r = 0; r < 4; r++) {
            float m = sv[0][r];
#pragma unroll
            for (int nt = 1; nt < 8; nt++) m = fmaxf(m, sv[nt][r]);
            m = fmaxf(m, __shfl_xor(m, 1));
            m = fmaxf(m, __shfl_xor(m, 2));
            m = fmaxf(m, __shfl_xor(m, 4));
            m = fmaxf(m, __shfl_xor(m, 8));
            float mnew = fmaxf(mprev[r], m);
            float alpha = __expf(mprev[r] - mnew);
            float s = 0.f;
#pragma unroll
            for (int nt = 0; nt < 8; nt++) {
                sv[nt][r] = __expf(sv[nt][r] - mnew);
                s += sv[nt][r];
            }
            s += __shfl_xor(s, 1); s += __shfl_xor(s, 2);
            s += __shfl_xor(s, 4); s += __shfl_xor(s, 8);
            lsum[r] = lsum[r] * alpha + s;
            mprev[r] = mnew;
#pragma unroll
            for (int nt = 0; nt < 4; nt++) o[nt][r] *= alpha;
        }
        __syncthreads();                             // B5: gather done -> P region
#pragma unroll
        for (int nt = 0; nt < 8; nt++)
#pragma unroll
            for (int r = 0; r < 4; r++)
                uni[(16 * w + quad * 4 + r) * LDV + nt * 16 + l16] = (bf16_t)sv[nt][r];
        __syncthreads();                             // B6: P visible

        // ---- PV: K-dim 128 = 4 chunks ----
        bf16x8 pa[4];
#pragma unroll
        for (int c = 0; c < 4; c++)
            pa[c] = *(const bf16x8*)&uni[(16 * w + l16) * LDV + c * 32 + quad * 8];
#pragma unroll
        for (int nt = 0; nt < 4; nt++) {
#pragma unroll
            for (int c = 0; c < 4; c++) {
                bf16x8 vb = *(const bf16x8*)&vt[(nt * 16 + l16) * LDV + c * 32 + quad * 8];
                o[nt] = __builtin_amdgcn_mfma_f32_16x16x32_bf16(pa[c], vb, o[nt], 0, 0, 0);
            }
        }
    }

    float inv[4];
#pragma unroll
    for (int r = 0; r < 4; r++) inv[r] = 1.f / lsum[r];
#pragma unroll
    for (int nt = 0; nt < 4; nt++)
#pragma unroll
        for (int r = 0; r < 4; r++) {
            int gi = i0 + 16 * w + quad * 4 + r;
            Out[(size_t)(b * SEQ + gi) * HID + n * DHEAD + nt * 16 + l16] = o[nt][r] * inv[r];
        }
}

extern "C" void kernel_launch(void* const* d_in, const int* in_sizes, int n_in,
                              void* d_out, int out_size, void* d_ws, size_t ws_size,
                              hipStream_t stream) {
    const float* hs  = (const float*)d_in[0];
    const float* r   = (const float*)d_in[1];
    const float* rwb = (const float*)d_in[2];
    const float* rrb = (const float*)d_in[3];
    const float* Wq  = (const float*)d_in[4];
    const float* bq  = (const float*)d_in[5];
    const float* Wk  = (const float*)d_in[6];
    const float* bk  = (const float*)d_in[7];
    const float* Wv  = (const float*)d_in[8];
    const float* bv  = (const float*)d_in[9];
    const float* Wr  = (const float*)d_in[10];

    // workspace map (bf16 elems), peak 58,720,256 B (same as round 3):
    // [0, 8.39M)    hsS  -> later: rS(4M) | WtR(2M) | dcorr(128K f32-as-256K)
    // [8.39M,14.7M) Wt3 [3072][2048]
    // [14.7M,18.9M) Qh ; [18.9M,23.1M) Kh ; [23.1M,27.3M) Vh ; [27.3M,29.4M) Rh
    bf16_t* ws0 = (bf16_t*)d_ws;
    bf16_t* hsS = ws0;
    bf16_t* Wt3 = ws0 + (size_t)4096 * KSPLIT;
    bf16_t* Qh  = Wt3 + (size_t)3072 * KSPLIT;
    bf16_t* Kh  = Qh + HEADSZ;
    bf16_t* Vh  = Kh + HEADSZ;
    bf16_t* Rh  = Vh + HEADSZ;
    bf16_t* rS  = ws0;                               // reuses hsS region
    bf16_t* WtR = ws0 + (size_t)2048 * KSPLIT;       // reuses hsS region
    float*  dcG = (float*)(ws0 + (size_t)3072 * KSPLIT);  // reuses hsS region

    dim3 blk(256);
    dim3 g_t(16, 16);

    // QKV (uses hsS)
    split_interleave<<<4096, blk, 0, stream>>>(hs, hsS, (BATCH * SEQ * HID) / 4);
    transpose_split<<<g_t, blk, 0, stream>>>(Wq, Wt3);
    transpose_split<<<g_t, blk, 0, stream>>>(Wk, Wt3 + (size_t)1024 * KSPLIT);
    transpose_split<<<g_t, blk, 0, stream>>>(Wv, Wt3 + (size_t)2048 * KSPLIT);
    gemm_qkv_fused<<<dim3(24, 32), blk, 0, stream>>>(hsS, Wt3, bq, bk, bv, Qh);

    // R (hsS dead -> reuse region for rS/WtR)
    split_interleave<<<2048, blk, 0, stream>>>(r, rS, (SEQ * HID) / 4);
    transpose_split<<<g_t, blk, 0, stream>>>(Wr, WtR);
    gemm_split_mfma<<<dim3(8, 16), blk, 0, stream>>>(rS, WtR, Rh);

    // dcorr table from Kh
    dcorr_kernel<<<(BATCH * NHEAD * SEQ) / 256, blk, 0, stream>>>(Kh, rwb, rrb, dcG);

    rel_attn_mfma2<<<dim3(SEQ / TQ, NHEAD, BATCH), blk, 0, stream>>>(
        Qh, Kh, Vh, Rh, rrb, dcG, (float*)d_out);
}

// Round 5
// 413.620 us; speedup vs baseline: 10.2560x; 1.2011x over previous
//
#include <hip/hip_runtime.h>
#include <math.h>

#define HID   1024
#define NHEAD 16
#define DHEAD 64
#define BATCH 2
#define SEQ   2048

#define TQ   64
#define TK2  128
#define NW2  191     // TQ+TK2-1 rel-shift band rows
#define LDP  136     // P stride (bf16 elems)
#define LDBT 68      // bandT stride: band[l][i'], i' in 0..64, +3 pad

#define KSPLIT 2048  // K' = 2*HID (hi/lo interleaved)
#define HEADSZ ((size_t)BATCH * SEQ * HID)

typedef __bf16 bf16_t;
typedef bf16_t bf16x8 __attribute__((ext_vector_type(8)));
typedef bf16_t bf16x4 __attribute__((ext_vector_type(4)));
typedef float  f32x4  __attribute__((ext_vector_type(4)));

__device__ __forceinline__ void load_lds16(const void* g, void* l) {
    __builtin_amdgcn_global_load_lds(
        (const __attribute__((address_space(1))) unsigned int*)g,
        (__attribute__((address_space(3))) unsigned int*)l, 16, 0, 0);
}

__device__ __forceinline__ void split2(float x, bf16_t* hi, bf16_t* lo) {
    bf16_t h = (bf16_t)x;
    *hi = h;
    *lo = (bf16_t)(x - (float)h);
}

// ---------------- prep 1: fp32 [M][1024] -> hi/lo-interleaved bf16 [M][2048]
__global__ __launch_bounds__(256) void split_interleave(
    const float* __restrict__ in, bf16_t* __restrict__ out, int n4)
{
    int g = blockIdx.x * 256 + threadIdx.x;
    if (g >= n4) return;
    float4 v = ((const float4*)in)[g];
    int m = g >> 8, c4 = g & 255;
    float xs[4] = {v.x, v.y, v.z, v.w};
    bf16x8 o;
#pragma unroll
    for (int e = 0; e < 4; e++) {
        bf16_t h, l; split2(xs[e], &h, &l);
        o[2 * e] = h; o[2 * e + 1] = l;
    }
    *(bf16x8*)(out + (size_t)m * KSPLIT + c4 * 8) = o;
}

// ---------------- prep 2: W fp32 [1024 k][1024 n] -> Wt' bf16 [1024 n][2048 k']
__global__ __launch_bounds__(256) void transpose_split(
    const float* __restrict__ W, bf16_t* __restrict__ Wt)
{
    __shared__ float t[64][65];
    const int tid = threadIdx.x;
    const int n0 = blockIdx.x * 64, k0 = blockIdx.y * 64;
    for (int idx = tid; idx < 1024; idx += 256) {
        int r = idx >> 4, c4 = (idx & 15) * 4;
        float4 v = *(const float4*)(W + (size_t)(k0 + r) * HID + n0 + c4);
        t[r][c4] = v.x; t[r][c4 + 1] = v.y; t[r][c4 + 2] = v.z; t[r][c4 + 3] = v.w;
    }
    __syncthreads();
    for (int idx = tid; idx < 1024; idx += 256) {
        int nr = idx >> 4, c4 = (idx & 15) * 4;
        bf16x8 o;
#pragma unroll
        for (int e = 0; e < 4; e++) {
            bf16_t h, l; split2(t[c4 + e][nr], &h, &l);
            o[2 * e] = h; o[2 * e + 1] = l;
        }
        *(bf16x8*)(Wt + (size_t)(n0 + nr) * KSPLIT + (k0 + c4) * 2) = o;
    }
}

// ---------------- fused QKV split-bf16 MFMA GEMM ----------------------------
// proj = bn>>10: 0=Q (+bq+rrb fused, single rounding), 1=K, 2=V (operand swap
// -> transposed [d][s] layout directly).
__global__ __launch_bounds__(256, 3) void gemm_qkv_fused(
    const bf16_t* __restrict__ A, const bf16_t* __restrict__ Wt3,
    const float* __restrict__ bq, const float* __restrict__ bk,
    const float* __restrict__ bv, const float* __restrict__ rrb,
    bf16_t* __restrict__ Cq)
{
    __shared__ bf16_t As[128 * 64];
    __shared__ bf16_t Bs[128 * 64];
    const int tid = threadIdx.x;
    const int w = tid >> 6, lane = tid & 63;
    const int quad = lane >> 4, l16 = lane & 15;
    const int bn = blockIdx.x * 128;
    const int bm = blockIdx.y * 128;
    const int proj = bn >> 10;
    const int vswap = (proj == 2);

    const int srow = tid >> 3;
    const int scg  = (tid & 7) ^ ((tid >> 3) & 7);
    const bf16_t* Ab = A   + (size_t)(bm + srow) * KSPLIT + scg * 8;
    const bf16_t* Bb = Wt3 + (size_t)(bn + srow) * KSPLIT + scg * 8;

    f32x4 acc[2][8];
#pragma unroll
    for (int i = 0; i < 2; i++)
#pragma unroll
        for (int j = 0; j < 8; j++) {
            acc[i][j][0] = 0.f; acc[i][j][1] = 0.f;
            acc[i][j][2] = 0.f; acc[i][j][3] = 0.f;
        }

    const bf16_t* P1 = vswap ? Bs : As;
    const bf16_t* P2 = vswap ? As : Bs;

    for (int k0 = 0; k0 < KSPLIT; k0 += 64) {
#pragma unroll
        for (int j = 0; j < 4; j++) {
            load_lds16(Ab + (size_t)j * 32 * KSPLIT + k0, &As[j * 2048 + w * 512]);
            load_lds16(Bb + (size_t)j * 32 * KSPLIT + k0, &Bs[j * 2048 + w * 512]);
        }
        __syncthreads();
        bf16x8 af[2][2];
#pragma unroll
        for (int mt = 0; mt < 2; mt++) {
            int r = w * 32 + mt * 16 + l16, rx = r & 7;
            int c0 = (quad ^ rx);
            af[mt][0] = *(const bf16x8*)&P1[r * 64 + c0 * 8];
            af[mt][1] = *(const bf16x8*)&P1[r * 64 + (c0 ^ 4) * 8];
        }
#pragma unroll
        for (int nt = 0; nt < 8; nt++) {
            int r = nt * 16 + l16, rx = r & 7;
            int c0 = (quad ^ rx);
            bf16x8 b0 = *(const bf16x8*)&P2[r * 64 + c0 * 8];
            bf16x8 b1 = *(const bf16x8*)&P2[r * 64 + (c0 ^ 4) * 8];
#pragma unroll
            for (int mt = 0; mt < 2; mt++) {
                acc[mt][nt] = __builtin_amdgcn_mfma_f32_16x16x32_bf16(af[mt][0], b0, acc[mt][nt], 0, 0, 0);
                acc[mt][nt] = __builtin_amdgcn_mfma_f32_16x16x32_bf16(af[mt][1], b1, acc[mt][nt], 0, 0, 0);
            }
        }
        __syncthreads();
    }

#pragma unroll
    for (int mt = 0; mt < 2; mt++)
#pragma unroll
        for (int nt = 0; nt < 8; nt++)
#pragma unroll
            for (int r4 = 0; r4 < 4; r4++) {
                int rowp = w * 32 + mt * 16 + quad * 4 + r4;
                int colp = nt * 16 + l16;
                float v = acc[mt][nt][r4];
                if (!vswap) {
                    int m = bm + rowp, nloc = (bn & 1023) + colp;
                    v += (proj == 0) ? (bq[nloc] + rrb[nloc]) : bk[nloc];
                    int bb = m >> 11, s = m & (SEQ - 1);
                    int nh = nloc >> 6, d = nloc & 63;
                    Cq[(size_t)proj * HEADSZ + (((size_t)(bb * NHEAD + nh) * SEQ + s) * DHEAD) + d] = (bf16_t)v;
                } else {
                    int nloc = (bn & 1023) + rowp, m = bm + colp;
                    v += bv[nloc];
                    int bb = m >> 11, s = m & (SEQ - 1);
                    int nh = nloc >> 6, d = nloc & 63;
                    Cq[(size_t)2 * HEADSZ + (((size_t)(bb * NHEAD + nh) * DHEAD + d) * SEQ) + s] = (bf16_t)v;
                }
            }
}

// ---------------- R projection (single, row layout) -------------------------
__global__ __launch_bounds__(256, 3) void gemm_split_mfma(
    const bf16_t* __restrict__ A, const bf16_t* __restrict__ Bw,
    bf16_t* __restrict__ C)
{
    __shared__ bf16_t As[128 * 64];
    __shared__ bf16_t Bs[128 * 64];
    const int tid = threadIdx.x;
    const int w = tid >> 6, lane = tid & 63;
    const int quad = lane >> 4, l16 = lane & 15;
    const int bn = blockIdx.x * 128;
    const int bm = blockIdx.y * 128;
    const int srow = tid >> 3;
    const int scg  = (tid & 7) ^ ((tid >> 3) & 7);
    const bf16_t* Ab = A  + (size_t)(bm + srow) * KSPLIT + scg * 8;
    const bf16_t* Bb = Bw + (size_t)(bn + srow) * KSPLIT + scg * 8;

    f32x4 acc[2][8];
#pragma unroll
    for (int i = 0; i < 2; i++)
#pragma unroll
        for (int j = 0; j < 8; j++) {
            acc[i][j][0] = 0.f; acc[i][j][1] = 0.f;
            acc[i][j][2] = 0.f; acc[i][j][3] = 0.f;
        }

    for (int k0 = 0; k0 < KSPLIT; k0 += 64) {
#pragma unroll
        for (int j = 0; j < 4; j++) {
            load_lds16(Ab + (size_t)j * 32 * KSPLIT + k0, &As[j * 2048 + w * 512]);
            load_lds16(Bb + (size_t)j * 32 * KSPLIT + k0, &Bs[j * 2048 + w * 512]);
        }
        __syncthreads();
        bf16x8 af[2][2];
#pragma unroll
        for (int mt = 0; mt < 2; mt++) {
            int r = w * 32 + mt * 16 + l16, rx = r & 7;
            int c0 = (quad ^ rx);
            af[mt][0] = *(const bf16x8*)&As[r * 64 + c0 * 8];
            af[mt][1] = *(const bf16x8*)&As[r * 64 + (c0 ^ 4) * 8];
        }
#pragma unroll
        for (int nt = 0; nt < 8; nt++) {
            int r = nt * 16 + l16, rx = r & 7;
            int c0 = (quad ^ rx);
            bf16x8 b0 = *(const bf16x8*)&Bs[r * 64 + c0 * 8];
            bf16x8 b1 = *(const bf16x8*)&Bs[r * 64 + (c0 ^ 4) * 8];
#pragma unroll
            for (int mt = 0; mt < 2; mt++) {
                acc[mt][nt] = __builtin_amdgcn_mfma_f32_16x16x32_bf16(af[mt][0], b0, acc[mt][nt], 0, 0, 0);
                acc[mt][nt] = __builtin_amdgcn_mfma_f32_16x16x32_bf16(af[mt][1], b1, acc[mt][nt], 0, 0, 0);
            }
        }
        __syncthreads();
    }
#pragma unroll
    for (int mt = 0; mt < 2; mt++)
#pragma unroll
        for (int nt = 0; nt < 8; nt++)
#pragma unroll
            for (int r4 = 0; r4 < 4; r4++) {
                int rowp = w * 32 + mt * 16 + quad * 4 + r4;
                int colp = nt * 16 + l16;
                int s = bm + rowp, n = bn + colp;
                int nh = n >> 6, d = n & 63;
                C[(((size_t)nh * SEQ + s) * DHEAD) + d] = (bf16_t)acc[mt][nt][r4];
            }
}

// ---------------- prep 3: dcorr[b,n,s] = (rwb-rrb) . K[b,n,s,:] -------------
__global__ __launch_bounds__(256) void dcorr_kernel(
    const bf16_t* __restrict__ Kh, const float* __restrict__ rwb,
    const float* __restrict__ rrb, float* __restrict__ dc)
{
    int g = blockIdx.x * 256 + threadIdx.x;
    int bn = g >> 11;
    int n = bn & (NHEAD - 1);
    const bf16_t* kr = Kh + (size_t)g * DHEAD;
    float a = 0.f;
#pragma unroll
    for (int c8 = 0; c8 < 8; c8++) {
        bf16x8 kv = *(const bf16x8*)(kr + c8 * 8);
#pragma unroll
        for (int e = 0; e < 8; e++) {
            int d = c8 * 8 + e;
            a = fmaf(rwb[n * DHEAD + d] - rrb[n * DHEAD + d], (float)kv[e], a);
        }
    }
    dc[g] = a;
}

// ---------------- MFMA flash rel-attention v3 --------------------------------
// qs = (q + bq + rrb) from GEMM (single rounding). AC = qs.K^T + dcorr[j].
// Band = qs.rkc^T, stored transposed bandT[l][i'] via b64 writes.
// Staging via global_load_lds w/ source-side XOR swizzle; zero-page for rr==SEQ.
// 4 barriers/tile: B1 (PV done) B2 (stage visible) B3 (frag reads done)
// B4 (band visible). P->PV is wave-local (no barrier).
__global__ __launch_bounds__(256, 2) void rel_attn_mfma3(
    const bf16_t* __restrict__ Qh, const bf16_t* __restrict__ Kh,
    const bf16_t* __restrict__ Vth, const bf16_t* __restrict__ Rkh,
    const float* __restrict__ dcorr, const bf16_t* __restrict__ zp,
    float* __restrict__ Out)
{
    __shared__ bf16_t qs[65 * 64];      // swizzled, stride 64
    __shared__ bf16_t ktP[64 * LDP];    // kt[128*64] U P[64*136]  (8704 elems)
    __shared__ bf16_t vt[64 * 128];     // [d][key], swizzled (mask 15)
    __shared__ bf16_t rkb[192 * LDBT];  // rkc[192*64] U bandT[192*68] (13056)
    __shared__ float dco[TK2];

    const int tid = threadIdx.x;
    const int w = tid >> 6, lane = tid & 63;
    const int quad = lane >> 4, l16 = lane & 15;
    const int i0 = blockIdx.x * TQ;
    const int n = blockIdx.y, b = blockIdx.z;

    const bf16_t* Qb = Qh + ((size_t)(b * NHEAD + n) * SEQ + i0) * DHEAD;
    const bf16_t* Kb = Kh + (size_t)(b * NHEAD + n) * SEQ * DHEAD;
    const bf16_t* Vb = Vth + (size_t)(b * NHEAD + n) * DHEAD * SEQ;
    const bf16_t* Rb = Rkh + (size_t)n * SEQ * DHEAD;
    const float*  Db = dcorr + (size_t)(b * NHEAD + n) * SEQ;

    // stage qs (rows i0..i0+64; row 64 zero if OOB), source-chunk swizzle
    for (int idx = tid; idx < 65 * 8; idx += 256) {
        int row = idx >> 3, p = idx & 7;
        int g = p ^ (row & 7);
        uint4 val = make_uint4(0, 0, 0, 0);
        if (i0 + row < SEQ) val = *(const uint4*)(Qb + row * DHEAD + g * 8);
        *(uint4*)&qs[row * 64 + p * 8] = val;
    }
    __syncthreads();

    // hoisted A-fragments (qs never changes)
    const int rq = 16 * w + l16;
    const int cq0 = quad ^ (rq & 7);
    const bf16x8 aq0 = *(const bf16x8*)&qs[rq * 64 + cq0 * 8];
    const bf16x8 aq1 = *(const bf16x8*)&qs[rq * 64 + (cq0 ^ 4) * 8];

    f32x4 o[4];
    float mprev[4], lsum[4];
#pragma unroll
    for (int t = 0; t < 4; t++) {
        o[t][0] = 0.f; o[t][1] = 0.f; o[t][2] = 0.f; o[t][3] = 0.f;
        mprev[t] = -3.0e38f; lsum[t] = 0.f;
    }
    const float C1 = 0.18033688f;   // 0.125 * log2(e)

    for (int j0 = 0; j0 < SEQ; j0 += TK2) {
        __syncthreads();                             // B1: prev PV reads done
        // ---- async staging: kt (16 grp), vt (16 grp), rkc (24 grp) ----
#pragma unroll
        for (int t = 0; t < 4; t++) {
            int r0 = (w + 4 * t) * 8;
            int row = r0 + (lane >> 3);
            int gch = (lane & 7) ^ (row & 7);
            load_lds16(Kb + (size_t)(j0 + row) * DHEAD + gch * 8, &ktP[r0 * 64]);
        }
#pragma unroll
        for (int t = 0; t < 4; t++) {
            int d0 = (w + 4 * t) * 4;
            int d = d0 + (lane >> 4);
            int gch = (lane & 15) ^ (d & 15);
            load_lds16(Vb + (size_t)d * SEQ + j0 + gch * 8, &vt[d0 * 128]);
        }
        const int base1 = SEQ + j0 - i0 - TQ;
#pragma unroll
        for (int t = 0; t < 6; t++) {
            int l0 = (w + 4 * t) * 8;
            int l = l0 + (lane >> 3);
            int rr = base1 + l;
            const bf16_t* rp = (rr < SEQ) ? (Rb + (size_t)rr * DHEAD)
                             : (rr > SEQ) ? (Rb + (size_t)(rr - SEQ - 1) * DHEAD) : zp;
            int gch = (lane & 7) ^ (l & 7);
            load_lds16(rp + gch * 8, &rkb[l0 * 64]);
        }
        if (tid < TK2) dco[tid] = Db[j0 + tid];
        __syncthreads();                             // B2: staging visible

        // ---- MFMA: AC (8x2) + band (12x2) ----
        f32x4 sac[8];
#pragma unroll
        for (int nt = 0; nt < 8; nt++) {
            int r = nt * 16 + l16;
            int c0 = quad ^ (r & 7);
            bf16x8 b0 = *(const bf16x8*)&ktP[r * 64 + c0 * 8];
            bf16x8 b1 = *(const bf16x8*)&ktP[r * 64 + (c0 ^ 4) * 8];
            f32x4 c; c[0] = 0.f; c[1] = 0.f; c[2] = 0.f; c[3] = 0.f;
            c = __builtin_amdgcn_mfma_f32_16x16x32_bf16(aq0, b0, c, 0, 0, 0);
            c = __builtin_amdgcn_mfma_f32_16x16x32_bf16(aq1, b1, c, 0, 0, 0);
            sac[nt] = c;
        }
        f32x4 bdc[12];
#pragma unroll
        for (int lt = 0; lt < 12; lt++) {
            int l = lt * 16 + l16;
            int c0 = quad ^ (l & 7);
            bf16x8 b0 = *(const bf16x8*)&rkb[l * 64 + c0 * 8];
            bf16x8 b1 = *(const bf16x8*)&rkb[l * 64 + (c0 ^ 4) * 8];
            f32x4 c; c[0] = 0.f; c[1] = 0.f; c[2] = 0.f; c[3] = 0.f;
            c = __builtin_amdgcn_mfma_f32_16x16x32_bf16(aq0, b0, c, 0, 0, 0);
            c = __builtin_amdgcn_mfma_f32_16x16x32_bf16(aq1, b1, c, 0, 0, 0);
            bdc[lt] = c;
        }
        // band row-64 (case-2 source for il=63): waves 2,3 cover l=0..127
        float bd64 = 0.f;
        if (w >= 2) {
            int l = (w - 2) * 64 + lane;
            int lx = l & 7;
#pragma unroll
            for (int c = 0; c < 8; c++) {
                bf16x8 qv = *(const bf16x8*)&qs[64 * 64 + c * 8];       // row 64: 64&7==0
                bf16x8 rv = *(const bf16x8*)&rkb[l * 64 + (c ^ lx) * 8];
#pragma unroll
                for (int e = 0; e < 8; e++) bd64 = fmaf((float)qv[e], (float)rv[e], bd64);
            }
        }
        __syncthreads();                             // B3: kt/rkc frag reads done

        // ---- band store, transposed: bandT[l][i'] (b64 writes) ----
#pragma unroll
        for (int lt = 0; lt < 12; lt++) {
            int l = lt * 16 + l16;
            bf16x4 pk;
#pragma unroll
            for (int r = 0; r < 4; r++) pk[r] = (bf16_t)bdc[lt][r];
            *(bf16x4*)&rkb[l * LDBT + 16 * w + quad * 4] = pk;
        }
        if (w >= 2) rkb[((w - 2) * 64 + lane) * LDBT + 64] = (bf16_t)bd64;
        __syncthreads();                             // B4: band visible

        // ---- gather + assemble (raw units) + online softmax (exp2) ----
        float sv[8][4];
#pragma unroll
        for (int nt = 0; nt < 8; nt++) {
            float dcv = dco[nt * 16 + l16];
#pragma unroll
            for (int r = 0; r < 4; r++) {
                int il = 16 * w + quad * 4 + r;
                int jl = nt * 16 + l16;
                int l = jl + (TQ - 1) - il;
                int rr = base1 + l;
                int ip = il + (rr > SEQ ? 1 : 0);
                float bd = (float)rkb[l * LDBT + ip];
                sv[nt][r] = sac[nt][r] + dcv + bd;
            }
        }
#pragma unroll
        for (int r = 0; r < 4; r++) {
            float m = sv[0][r];
#pragma unroll
            for (int nt = 1; nt < 8; nt++) m = fmaxf(m, sv[nt][r]);
            m = fmaxf(m, __shfl_xor(m, 1));
            m = fmaxf(m, __shfl_xor(m, 2));
            m = fmaxf(m, __shfl_xor(m, 4));
            m = fmaxf(m, __shfl_xor(m, 8));
            float mnew = fmaxf(mprev[r], m);
            float alpha = exp2f((mprev[r] - mnew) * C1);
            float s = 0.f;
#pragma unroll
            for (int nt = 0; nt < 8; nt++) {
                sv[nt][r] = exp2f((sv[nt][r] - mnew) * C1);
                s += sv[nt][r];
            }
            s += __shfl_xor(s, 1); s += __shfl_xor(s, 2);
            s += __shfl_xor(s, 4); s += __shfl_xor(s, 8);
            lsum[r] = lsum[r] * alpha + s;
            mprev[r] = mnew;
#pragma unroll
            for (int nt = 0; nt < 4; nt++) o[nt][r] *= alpha;
        }

        // ---- P store (into kt region; kt reads done at B3; wave-local rows)
#pragma unroll
        for (int nt = 0; nt < 8; nt++)
#pragma unroll
            for (int r = 0; r < 4; r++)
                ktP[(16 * w + quad * 4 + r) * LDP + nt * 16 + l16] = (bf16_t)sv[nt][r];

        // ---- PV (P rows are wave-local: no barrier needed) ----
        bf16x8 pa[4];
#pragma unroll
        for (int c = 0; c < 4; c++)
            pa[c] = *(const bf16x8*)&ktP[(16 * w + l16) * LDP + c * 32 + quad * 8];
#pragma unroll
        for (int nt = 0; nt < 4; nt++) {
#pragma unroll
            for (int c = 0; c < 4; c++) {
                int dv = nt * 16 + l16;
                int gch = (4 * c + quad) ^ (dv & 15);
                bf16x8 vb = *(const bf16x8*)&vt[dv * 128 + gch * 8];
                o[nt] = __builtin_amdgcn_mfma_f32_16x16x32_bf16(pa[c], vb, o[nt], 0, 0, 0);
            }
        }
    }

    float inv[4];
#pragma unroll
    for (int r = 0; r < 4; r++) inv[r] = 1.f / lsum[r];
#pragma unroll
    for (int nt = 0; nt < 4; nt++)
#pragma unroll
        for (int r = 0; r < 4; r++) {
            int gi = i0 + 16 * w + quad * 4 + r;
            Out[(size_t)(b * SEQ + gi) * HID + n * DHEAD + nt * 16 + l16] = o[nt][r] * inv[r];
        }
}

extern "C" void kernel_launch(void* const* d_in, const int* in_sizes, int n_in,
                              void* d_out, int out_size, void* d_ws, size_t ws_size,
                              hipStream_t stream) {
    const float* hs  = (const float*)d_in[0];
    const float* r   = (const float*)d_in[1];
    const float* rwb = (const float*)d_in[2];
    const float* rrb = (const float*)d_in[3];
    const float* Wq  = (const float*)d_in[4];
    const float* bq  = (const float*)d_in[5];
    const float* Wk  = (const float*)d_in[6];
    const float* bk  = (const float*)d_in[7];
    const float* Wv  = (const float*)d_in[8];
    const float* bv  = (const float*)d_in[9];
    const float* Wr  = (const float*)d_in[10];

    // workspace map (bf16 elems), peak 58,720,256 B:
    // [0, 8.39M)    hsS  -> later: rS(4.19M) | WtR(2.10M) | dcorr(128K f32) | zp
    // [8.39M,14.7M) Wt3 ; then Qh/Kh/Vh/Rh
    bf16_t* ws0 = (bf16_t*)d_ws;
    bf16_t* hsS = ws0;
    bf16_t* Wt3 = ws0 + (size_t)4096 * KSPLIT;
    bf16_t* Qh  = Wt3 + (size_t)3072 * KSPLIT;
    bf16_t* Kh  = Qh + HEADSZ;
    bf16_t* Vh  = Kh + HEADSZ;
    bf16_t* Rh  = Vh + HEADSZ;
    bf16_t* rS  = ws0;                                    // reuses hsS region
    bf16_t* WtR = ws0 + (size_t)2048 * KSPLIT;            // reuses hsS region
    float*  dcG = (float*)(ws0 + (size_t)3072 * KSPLIT);  // reuses hsS region
    bf16_t* zp  = ws0 + (size_t)3072 * KSPLIT + 2 * BATCH * NHEAD * SEQ;  // after dcorr

    dim3 blk(256);
    dim3 g_t(16, 16);

    // QKV (uses hsS)
    split_interleave<<<4096, blk, 0, stream>>>(hs, hsS, (BATCH * SEQ * HID) / 4);
    transpose_split<<<g_t, blk, 0, stream>>>(Wq, Wt3);
    transpose_split<<<g_t, blk, 0, stream>>>(Wk, Wt3 + (size_t)1024 * KSPLIT);
    transpose_split<<<g_t, blk, 0, stream>>>(Wv, Wt3 + (size_t)2048 * KSPLIT);
    gemm_qkv_fused<<<dim3(24, 32), blk, 0, stream>>>(hsS, Wt3, bq, bk, bv, rrb, Qh);

    // R (hsS dead -> reuse region)
    split_interleave<<<2048, blk, 0, stream>>>(r, rS, (SEQ * HID) / 4);
    transpose_split<<<g_t, blk, 0, stream>>>(Wr, WtR);
    gemm_split_mfma<<<dim3(8, 16), blk, 0, stream>>>(rS, WtR, Rh);

    // dcorr table + zero page (ws is poisoned 0xAA each call -> re-zero)
    dcorr_kernel<<<(BATCH * NHEAD * SEQ) / 256, blk, 0, stream>>>(Kh, rwb, rrb, dcG);
    hipMemsetAsync(zp, 0, 256, stream);

    rel_attn_mfma3<<<dim3(SEQ / TQ, NHEAD, BATCH), blk, 0, stream>>>(
        Qh, Kh, Vh, Rh, dcG, zp, (float*)d_out);
}